// Round 4
// baseline (255.433 us; speedup 1.0000x reference)
//
#include <hip/hip_runtime.h>
#include <hip/hip_bf16.h>

#define B_   2
#define T_   2048
#define C_   1024
#define H_   16
#define KV_  4
#define HD_  64
#define M_   (B_*T_)     // 4096 tokens
#define NQKV_ 1536       // 1024 q + 256 k + 256 v
#define ST_  72          // LDS row stride (bf16 elems): 144 B

typedef __bf16 bf16x8 __attribute__((ext_vector_type(8)));
typedef float  f32x4  __attribute__((ext_vector_type(4)));

static __device__ __forceinline__ unsigned short f2bf(float f) {
    __hip_bfloat16 h = __float2bfloat16(f);
    return __builtin_bit_cast(unsigned short, h);
}

// ---------------------------------------------------------------- cast x -> bf16
__global__ void cast_x_kernel(const float* __restrict__ x, unsigned short* __restrict__ xb) {
    int i = (blockIdx.x * 256 + threadIdx.x) * 4;
    float4 v = *(const float4*)(x + i);
    ushort4 o = make_ushort4(f2bf(v.x), f2bf(v.y), f2bf(v.z), f2bf(v.w));
    *(ushort4*)(xb + i) = o;
}

// --------------------------------------- all 4 weight transposes in one launch
__global__ void transpose4_kernel(const float* __restrict__ Wq, const float* __restrict__ Wk,
                                  const float* __restrict__ Wv, const float* __restrict__ Wo,
                                  unsigned short* __restrict__ wtqkv, unsigned short* __restrict__ wto) {
    __shared__ float tile[32][33];
    int bid = blockIdx.x;
    const float* src; unsigned short* dst; int s, nlog;
    if (bid < 1024)      { src = Wq; dst = wtqkv;               s = bid;        nlog = 5; }
    else if (bid < 1280) { src = Wk; dst = wtqkv + 1024 * 1024; s = bid - 1024; nlog = 3; }
    else if (bid < 1536) { src = Wv; dst = wtqkv + 1280 * 1024; s = bid - 1280; nlog = 3; }
    else                 { src = Wo; dst = wto;                 s = bid - 1536; nlog = 5; }
    int N  = 32 << nlog;
    int k0 = (s >> nlog) * 32, n0 = (s & ((1 << nlog) - 1)) * 32;
    int lr = threadIdx.x >> 5, lc = threadIdx.x & 31;
    #pragma unroll
    for (int i = 0; i < 4; i++) {
        int r = lr + i * 8;
        tile[r][lc] = src[(k0 + r) * N + n0 + lc];
    }
    __syncthreads();
    #pragma unroll
    for (int i = 0; i < 4; i++) {
        int r = lr + i * 8;
        dst[(n0 + r) * 1024 + k0 + lc] = f2bf(tile[lc][r]);
    }
}

// ------------------------------------------------ 128x64 bf16 MFMA GEMM, K=1024, BK=32
// C = A (M x 1024) * Bt^T ; wave w owns rows w*32..+31 x all 64 cols (one head).
// ROPE=true: fused RoPE+RMSNorm epilogue (heads 0..15 q *0.125, 16..19 k, 20..23 v pass).
template <typename T, bool ROPE>
__global__ __launch_bounds__(256) void gemm_kernel(const unsigned short* __restrict__ A,
                                                   const unsigned short* __restrict__ Bt,
                                                   T* __restrict__ Cm, int Ni,
                                                   const float* __restrict__ cosb,
                                                   const float* __restrict__ sinb) {
    __shared__ __align__(16) unsigned short As[128 * 32];
    __shared__ __align__(16) unsigned short Bs[64 * 32];
    int m0 = blockIdx.x * 128;
    int head = blockIdx.y;
    int n0 = head * 64;
    int tid = threadIdx.x;
    int w = tid >> 6, lane = tid & 63;
    int col = lane & 15, quad = lane >> 4;
    int wm = w * 32;
    int ar = tid >> 2, ak = (tid & 3) * 8;   // A rows ar, ar+64 ; B row ar (0..63)

    f32x4 acc[2][4];
    #pragma unroll
    for (int mt = 0; mt < 2; mt++)
        #pragma unroll
        for (int nt = 0; nt < 4; nt++) acc[mt][nt] = (f32x4){0.f, 0.f, 0.f, 0.f};

    for (int k0 = 0; k0 < 1024; k0 += 32) {
        __builtin_amdgcn_global_load_lds(
            (const __attribute__((address_space(1))) unsigned int*)(A + (size_t)(m0 + ar) * 1024 + k0 + ak),
            (__attribute__((address_space(3))) unsigned int*)(As + ar * 32 + ak), 16, 0, 0);
        __builtin_amdgcn_global_load_lds(
            (const __attribute__((address_space(1))) unsigned int*)(A + (size_t)(m0 + ar + 64) * 1024 + k0 + ak),
            (__attribute__((address_space(3))) unsigned int*)(As + (ar + 64) * 32 + ak), 16, 0, 0);
        __builtin_amdgcn_global_load_lds(
            (const __attribute__((address_space(1))) unsigned int*)(Bt + (size_t)(n0 + ar) * 1024 + k0 + ak),
            (__attribute__((address_space(3))) unsigned int*)(Bs + ar * 32 + ak), 16, 0, 0);
        __syncthreads();
        bf16x8 af[2], bfr[4];
        #pragma unroll
        for (int mt = 0; mt < 2; mt++) af[mt]  = *(const bf16x8*)&As[(wm + mt * 16 + col) * 32 + quad * 8];
        #pragma unroll
        for (int nt = 0; nt < 4; nt++) bfr[nt] = *(const bf16x8*)&Bs[(nt * 16 + col) * 32 + quad * 8];
        #pragma unroll
        for (int mt = 0; mt < 2; mt++)
            #pragma unroll
            for (int nt = 0; nt < 4; nt++)
                acc[mt][nt] = __builtin_amdgcn_mfma_f32_16x16x32_bf16(af[mt], bfr[nt], acc[mt][nt], 0, 0, 0);
        __syncthreads();
    }

    if constexpr (ROPE) {
        if (head < H_ + KV_) {   // q or k head: RoPE + RMSNorm
            #pragma unroll
            for (int mt = 0; mt < 2; mt++)
                #pragma unroll
                for (int r = 0; r < 4; r++) {
                    int t = (m0 + wm + mt * 16 + quad * 4 + r) & (T_ - 1);
                    float nv[4];
                    #pragma unroll
                    for (int nt = 0; nt < 4; nt++) {
                        int i = (nt & 1) * 16 + col;
                        float c = cosb[t * 32 + i], s = sinb[t * 32 + i];
                        float v = acc[mt][nt][r], p = acc[mt][nt ^ 2][r];
                        nv[nt] = (nt < 2) ? (v * c + p * s) : (v * c - p * s);
                    }
                    float sq = nv[0] * nv[0] + nv[1] * nv[1] + nv[2] * nv[2] + nv[3] * nv[3];
                    sq += __shfl_xor(sq, 1, 64);
                    sq += __shfl_xor(sq, 2, 64);
                    sq += __shfl_xor(sq, 4, 64);
                    sq += __shfl_xor(sq, 8, 64);
                    float rr = rsqrtf(sq * (1.0f / 64.0f) + 1e-6f);
                    if (head < H_) rr *= 0.125f;   // fold attn scale into q
                    #pragma unroll
                    for (int nt = 0; nt < 4; nt++) acc[mt][nt][r] = nv[nt] * rr;
                }
        }
    }

    #pragma unroll
    for (int mt = 0; mt < 2; mt++)
        #pragma unroll
        for (int nt = 0; nt < 4; nt++)
            #pragma unroll
            for (int r = 0; r < 4; r++) {
                size_t idx = (size_t)(m0 + wm + mt * 16 + quad * 4 + r) * Ni + n0 + nt * 16 + col;
                if constexpr (sizeof(T) == 2) Cm[idx] = f2bf(acc[mt][nt][r]);
                else                          Cm[idx] = acc[mt][nt][r];
            }
}

// ------------------------------------------------ V -> V^T global: vtb[(b*KV+kvh)][d][t]
__global__ __launch_bounds__(256) void vtrans_kernel(const unsigned short* __restrict__ qkvb,
                                                     unsigned short* __restrict__ vtb) {
    __shared__ unsigned short tileb[64][72];
    int tile = blockIdx.x & 31;
    int bkv  = blockIdx.x >> 5;
    int b = bkv >> 2, kvh = bkv & 3;
    int tid = threadIdx.x;
    int t0 = tile * 64;
    #pragma unroll
    for (int i = 0; i < 2; i++) {
        int idx = tid + i * 256;
        int r = idx >> 3, d8 = (idx & 7) * 8;
        *(uint4*)&tileb[r][d8] =
            *(const uint4*)&qkvb[(size_t)(b * T_ + t0 + r) * NQKV_ + 1280 + kvh * 64 + d8];
    }
    __syncthreads();
    #pragma unroll
    for (int i = 0; i < 2; i++) {
        int idx = tid + i * 256;
        int dr = idx >> 3, t8 = (idx & 7) * 8;
        unsigned short tmp[8];
        #pragma unroll
        for (int j = 0; j < 8; j++) tmp[j] = tileb[t8 + j][dr];
        *(uint4*)&vtb[((size_t)(bkv * 64 + dr)) * T_ + t0 + t8] = *(uint4*)tmp;
    }
}

// ------------------------------------------------ MFMA flash attention, 128-query tiles
// block = (b, h, qt); qt DESCENDING in blockIdx for load balance (iters = 2qt+2).
// 4 waves; wave w owns q rows w*32..+31 (mt=2); K/V^T double-buffered, 1 barrier/iter.
__global__ __launch_bounds__(256) void attn_kernel(const unsigned short* __restrict__ qkvb,
                                                   const unsigned short* __restrict__ vtb,
                                                   unsigned short* __restrict__ yb) {
    __shared__ __align__(16) unsigned short Qs[128 * ST_];
    __shared__ __align__(16) unsigned short Ks[2][64 * ST_];
    __shared__ __align__(16) unsigned short Vts[2][64 * ST_];
    __shared__ __align__(16) unsigned short Ps[128 * ST_];

    int bh = blockIdx.x & 31;
    int qt = 15 - (blockIdx.x >> 5);      // big blocks dispatch first
    int b = bh >> 4, h = bh & 15, kvh = h >> 2;
    int tid = threadIdx.x;
    int w = tid >> 6, lane = tid & 63;
    int col = lane & 15, quad = lane >> 4;
    int nkt = 2 * qt + 2;
    int tau0 = qt * 128;

    size_t kbase = (size_t)(b * T_) * NQKV_ + 1024 + kvh * 64;
    size_t vbase = (size_t)((b * KV_ + kvh) * 64) * T_;

    // K/V staging: row sr (0..63), cols sd, sd+32
    int sr = tid >> 2, sd = (tid & 3) * 8;

    // Q staging (wave-private): rows w*32 + (lane>>1), 4x uint4
    int qr = w * 32 + (lane >> 1), qc = (lane & 1) * 32;
    #pragma unroll
    for (int j = 0; j < 4; j++)
        *(uint4*)&Qs[qr * ST_ + qc + ((j & 1) * 8) + ((j >> 1) * 16)] =
            *(const uint4*)&qkvb[(size_t)(b * T_ + tau0 + qr) * NQKV_ + h * 64 + qc + ((j & 1) * 8) + ((j >> 1) * 16)];

    // preload + stage tile 0
    uint4 kreg[2], vreg[2];
    #pragma unroll
    for (int c = 0; c < 2; c++) {
        kreg[c] = *(const uint4*)&qkvb[kbase + (size_t)sr * NQKV_ + sd + c * 32];
        vreg[c] = *(const uint4*)&vtb[vbase + (size_t)sr * T_ + sd + c * 32];
    }
    #pragma unroll
    for (int c = 0; c < 2; c++) {
        *(uint4*)&Ks[0][sr * ST_ + sd + c * 32]  = kreg[c];
        *(uint4*)&Vts[0][sr * ST_ + sd + c * 32] = vreg[c];
    }
    __syncthreads();

    float mrow[2][4], lrow[2][4];
    #pragma unroll
    for (int mt = 0; mt < 2; mt++)
        #pragma unroll
        for (int r = 0; r < 4; r++) { mrow[mt][r] = -1e30f; lrow[mt][r] = 0.f; }
    f32x4 o[2][4];
    #pragma unroll
    for (int mt = 0; mt < 2; mt++)
        #pragma unroll
        for (int nt = 0; nt < 4; nt++) o[mt][nt] = (f32x4){0.f, 0.f, 0.f, 0.f};

    for (int kt = 0; kt < nkt; kt++) {
        int cur = kt & 1;
        if (kt + 1 < nkt) {
            #pragma unroll
            for (int c = 0; c < 2; c++) {
                kreg[c] = *(const uint4*)&qkvb[kbase + (size_t)((kt + 1) * 64 + sr) * NQKV_ + sd + c * 32];
                vreg[c] = *(const uint4*)&vtb[vbase + (size_t)sr * T_ + (kt + 1) * 64 + sd + c * 32];
            }
        }
        // S = Q K^T : 32q x 64k per wave
        f32x4 sacc[2][4];
        #pragma unroll
        for (int mt = 0; mt < 2; mt++)
            #pragma unroll
            for (int nt = 0; nt < 4; nt++) sacc[mt][nt] = (f32x4){0.f, 0.f, 0.f, 0.f};
        #pragma unroll
        for (int step = 0; step < 2; step++) {
            bf16x8 aq[2];
            #pragma unroll
            for (int mt = 0; mt < 2; mt++)
                aq[mt] = *(const bf16x8*)&Qs[(w * 32 + mt * 16 + col) * ST_ + quad * 8 + step * 32];
            #pragma unroll
            for (int nt = 0; nt < 4; nt++) {
                bf16x8 kb = *(const bf16x8*)&Ks[cur][(nt * 16 + col) * ST_ + quad * 8 + step * 32];
                #pragma unroll
                for (int mt = 0; mt < 2; mt++)
                    sacc[mt][nt] = __builtin_amdgcn_mfma_f32_16x16x32_bf16(aq[mt], kb, sacc[mt][nt], 0, 0, 0);
            }
        }
        if (kt >= 2 * qt) {   // diagonal region: per-element causal mask
            #pragma unroll
            for (int mt = 0; mt < 2; mt++)
                #pragma unroll
                for (int nt = 0; nt < 4; nt++)
                    #pragma unroll
                    for (int r = 0; r < 4; r++)
                        if (kt * 64 + nt * 16 + col > tau0 + w * 32 + mt * 16 + quad * 4 + r)
                            sacc[mt][nt][r] = -1e30f;
        }
        // online softmax: lane owns 8 rows (mt, r); reduce across 16 col-lanes
        float alpha[2][4];
        #pragma unroll
        for (int mt = 0; mt < 2; mt++)
            #pragma unroll
            for (int r = 0; r < 4; r++) {
                float mx = fmaxf(fmaxf(sacc[mt][0][r], sacc[mt][1][r]), fmaxf(sacc[mt][2][r], sacc[mt][3][r]));
                mx = fmaxf(mx, __shfl_xor(mx, 1, 64));
                mx = fmaxf(mx, __shfl_xor(mx, 2, 64));
                mx = fmaxf(mx, __shfl_xor(mx, 4, 64));
                mx = fmaxf(mx, __shfl_xor(mx, 8, 64));
                float mnew = fmaxf(mrow[mt][r], mx);
                alpha[mt][r] = __expf(mrow[mt][r] - mnew);
                float rs = 0.f;
                #pragma unroll
                for (int nt = 0; nt < 4; nt++) {
                    float pv = __expf(sacc[mt][nt][r] - mnew);
                    sacc[mt][nt][r] = pv;
                    rs += pv;
                }
                rs += __shfl_xor(rs, 1, 64);
                rs += __shfl_xor(rs, 2, 64);
                rs += __shfl_xor(rs, 4, 64);
                rs += __shfl_xor(rs, 8, 64);
                lrow[mt][r] = lrow[mt][r] * alpha[mt][r] + rs;
                mrow[mt][r] = mnew;
            }
        // P -> LDS (wave-private stripe)
        #pragma unroll
        for (int mt = 0; mt < 2; mt++)
            #pragma unroll
            for (int nt = 0; nt < 4; nt++)
                #pragma unroll
                for (int r = 0; r < 4; r++)
                    Ps[(w * 32 + mt * 16 + quad * 4 + r) * ST_ + nt * 16 + col] = f2bf(sacc[mt][nt][r]);
        #pragma unroll
        for (int mt = 0; mt < 2; mt++)
            #pragma unroll
            for (int nt = 0; nt < 4; nt++)
                #pragma unroll
                for (int r = 0; r < 4; r++)
                    o[mt][nt][r] *= alpha[mt][r];
        // O += P V
        #pragma unroll
        for (int step = 0; step < 2; step++) {
            bf16x8 ap[2];
            #pragma unroll
            for (int mt = 0; mt < 2; mt++)
                ap[mt] = *(const bf16x8*)&Ps[(w * 32 + mt * 16 + col) * ST_ + quad * 8 + step * 32];
            #pragma unroll
            for (int nt = 0; nt < 4; nt++) {
                bf16x8 vb = *(const bf16x8*)&Vts[cur][(nt * 16 + col) * ST_ + quad * 8 + step * 32];
                #pragma unroll
                for (int mt = 0; mt < 2; mt++)
                    o[mt][nt] = __builtin_amdgcn_mfma_f32_16x16x32_bf16(ap[mt], vb, o[mt][nt], 0, 0, 0);
            }
        }
        if (kt + 1 < nkt) {
            #pragma unroll
            for (int c = 0; c < 2; c++) {
                *(uint4*)&Ks[cur ^ 1][sr * ST_ + sd + c * 32]  = kreg[c];
                *(uint4*)&Vts[cur ^ 1][sr * ST_ + sd + c * 32] = vreg[c];
            }
        }
        __syncthreads();
    }

    #pragma unroll
    for (int mt = 0; mt < 2; mt++)
        #pragma unroll
        for (int r = 0; r < 4; r++) {
            float inv = 1.0f / lrow[mt][r];
            size_t row = (size_t)(b * T_ + tau0 + w * 32 + mt * 16 + quad * 4 + r) * C_ + h * 64;
            #pragma unroll
            for (int nt = 0; nt < 4; nt++)
                yb[row + nt * 16 + col] = f2bf(o[mt][nt][r] * inv);
        }
}

// ---------------------------------------------------------------- launch
extern "C" void kernel_launch(void* const* d_in, const int* in_sizes, int n_in,
                              void* d_out, int out_size, void* d_ws, size_t ws_size,
                              hipStream_t stream) {
    const float* x    = (const float*)d_in[0];
    const float* cosb = (const float*)d_in[1];
    const float* sinb = (const float*)d_in[2];
    const float* Wq   = (const float*)d_in[3];
    const float* Wk   = (const float*)d_in[4];
    const float* Wv   = (const float*)d_in[5];
    const float* Wo   = (const float*)d_in[6];
    float* out = (float*)d_out;

    char* ws = (char*)d_ws;
    unsigned short* xb    = (unsigned short*)(ws);               // 8 MB (reused as yb)
    unsigned short* yb    = (unsigned short*)(ws);               // alias: xb dead after QKV GEMM
    unsigned short* wtqkv = (unsigned short*)(ws + ( 8u << 20)); // 3 MB
    unsigned short* wto   = (unsigned short*)(ws + (11u << 20)); // 2 MB
    unsigned short* qkvb  = (unsigned short*)(ws + (13u << 20)); // 12 MB
    unsigned short* vtb   = (unsigned short*)(ws + (25u << 20)); // 2 MB

    cast_x_kernel<<<4096, 256, 0, stream>>>(x, xb);
    transpose4_kernel<<<2560, 256, 0, stream>>>(Wq, Wk, Wv, Wo, wtqkv, wto);
    // QKV projection + fused RoPE/RMSNorm -> bf16 qkv
    gemm_kernel<unsigned short, true><<<dim3(32, 24), 256, 0, stream>>>(xb, wtqkv, qkvb, NQKV_, cosb, sinb);
    vtrans_kernel<<<256, 256, 0, stream>>>(qkvb, vtb);
    attn_kernel<<<512, 256, 0, stream>>>(qkvb, vtb, yb);
    // output projection -> fp32 out
    gemm_kernel<float, false><<<dim3(32, 16), 256, 0, stream>>>(yb, wto, out, C_, nullptr, nullptr);
}

// Round 5
// 240.200 us; speedup vs baseline: 1.0634x; 1.0634x over previous
//
#include <hip/hip_runtime.h>
#include <hip/hip_bf16.h>

#define B_   2
#define T_   2048
#define C_   1024
#define H_   16
#define KV_  4
#define HD_  64
#define M_   (B_*T_)     // 4096 tokens
#define NQKV_ 1536       // 1024 q + 256 k + 256 v
#define ST_  72          // LDS row stride (bf16 elems): 144 B

typedef __bf16 bf16x8 __attribute__((ext_vector_type(8)));
typedef float  f32x4  __attribute__((ext_vector_type(4)));

static __device__ __forceinline__ unsigned short f2bf(float f) {
    __hip_bfloat16 h = __float2bfloat16(f);
    return __builtin_bit_cast(unsigned short, h);
}

// ---------------------------------------------------------------- cast x -> bf16
__global__ void cast_x_kernel(const float* __restrict__ x, unsigned short* __restrict__ xb) {
    int i = (blockIdx.x * 256 + threadIdx.x) * 4;
    float4 v = *(const float4*)(x + i);
    ushort4 o = make_ushort4(f2bf(v.x), f2bf(v.y), f2bf(v.z), f2bf(v.w));
    *(ushort4*)(xb + i) = o;
}

// --------------------------------------- all 4 weight transposes in one launch
__global__ void transpose4_kernel(const float* __restrict__ Wq, const float* __restrict__ Wk,
                                  const float* __restrict__ Wv, const float* __restrict__ Wo,
                                  unsigned short* __restrict__ wtqkv, unsigned short* __restrict__ wto) {
    __shared__ float tile[32][33];
    int bid = blockIdx.x;
    const float* src; unsigned short* dst; int s, nlog;
    if (bid < 1024)      { src = Wq; dst = wtqkv;               s = bid;        nlog = 5; }
    else if (bid < 1280) { src = Wk; dst = wtqkv + 1024 * 1024; s = bid - 1024; nlog = 3; }
    else if (bid < 1536) { src = Wv; dst = wtqkv + 1280 * 1024; s = bid - 1280; nlog = 3; }
    else                 { src = Wo; dst = wto;                 s = bid - 1536; nlog = 5; }
    int N  = 32 << nlog;
    int k0 = (s >> nlog) * 32, n0 = (s & ((1 << nlog) - 1)) * 32;
    int lr = threadIdx.x >> 5, lc = threadIdx.x & 31;
    #pragma unroll
    for (int i = 0; i < 4; i++) {
        int r = lr + i * 8;
        tile[r][lc] = src[(k0 + r) * N + n0 + lc];
    }
    __syncthreads();
    #pragma unroll
    for (int i = 0; i < 4; i++) {
        int r = lr + i * 8;
        dst[(n0 + r) * 1024 + k0 + lc] = f2bf(tile[lc][r]);
    }
}

// ------------------------------------------------ 128x64 bf16 MFMA GEMM, K=1024, BK=32
// ROPE=true: fused RoPE+RMSNorm epilogue (heads 0..15 q *0.125, 16..19 k, 20..23 v pass).
template <typename T, bool ROPE>
__global__ __launch_bounds__(256) void gemm_kernel(const unsigned short* __restrict__ A,
                                                   const unsigned short* __restrict__ Bt,
                                                   T* __restrict__ Cm, int Ni,
                                                   const float* __restrict__ cosb,
                                                   const float* __restrict__ sinb) {
    __shared__ __align__(16) unsigned short As[128 * 32];
    __shared__ __align__(16) unsigned short Bs[64 * 32];
    int m0 = blockIdx.x * 128;
    int head = blockIdx.y;
    int n0 = head * 64;
    int tid = threadIdx.x;
    int w = tid >> 6, lane = tid & 63;
    int col = lane & 15, quad = lane >> 4;
    int wm = w * 32;
    int ar = tid >> 2, ak = (tid & 3) * 8;

    f32x4 acc[2][4];
    #pragma unroll
    for (int mt = 0; mt < 2; mt++)
        #pragma unroll
        for (int nt = 0; nt < 4; nt++) acc[mt][nt] = (f32x4){0.f, 0.f, 0.f, 0.f};

    for (int k0 = 0; k0 < 1024; k0 += 32) {
        __builtin_amdgcn_global_load_lds(
            (const __attribute__((address_space(1))) unsigned int*)(A + (size_t)(m0 + ar) * 1024 + k0 + ak),
            (__attribute__((address_space(3))) unsigned int*)(As + ar * 32 + ak), 16, 0, 0);
        __builtin_amdgcn_global_load_lds(
            (const __attribute__((address_space(1))) unsigned int*)(A + (size_t)(m0 + ar + 64) * 1024 + k0 + ak),
            (__attribute__((address_space(3))) unsigned int*)(As + (ar + 64) * 32 + ak), 16, 0, 0);
        __builtin_amdgcn_global_load_lds(
            (const __attribute__((address_space(1))) unsigned int*)(Bt + (size_t)(n0 + ar) * 1024 + k0 + ak),
            (__attribute__((address_space(3))) unsigned int*)(Bs + ar * 32 + ak), 16, 0, 0);
        __syncthreads();
        bf16x8 af[2], bfr[4];
        #pragma unroll
        for (int mt = 0; mt < 2; mt++) af[mt]  = *(const bf16x8*)&As[(wm + mt * 16 + col) * 32 + quad * 8];
        #pragma unroll
        for (int nt = 0; nt < 4; nt++) bfr[nt] = *(const bf16x8*)&Bs[(nt * 16 + col) * 32 + quad * 8];
        #pragma unroll
        for (int mt = 0; mt < 2; mt++)
            #pragma unroll
            for (int nt = 0; nt < 4; nt++)
                acc[mt][nt] = __builtin_amdgcn_mfma_f32_16x16x32_bf16(af[mt], bfr[nt], acc[mt][nt], 0, 0, 0);
        __syncthreads();
    }

    if constexpr (ROPE) {
        if (head < H_ + KV_) {
            #pragma unroll
            for (int mt = 0; mt < 2; mt++)
                #pragma unroll
                for (int r = 0; r < 4; r++) {
                    int t = (m0 + wm + mt * 16 + quad * 4 + r) & (T_ - 1);
                    float nv[4];
                    #pragma unroll
                    for (int nt = 0; nt < 4; nt++) {
                        int i = (nt & 1) * 16 + col;
                        float c = cosb[t * 32 + i], s = sinb[t * 32 + i];
                        float v = acc[mt][nt][r], p = acc[mt][nt ^ 2][r];
                        nv[nt] = (nt < 2) ? (v * c + p * s) : (v * c - p * s);
                    }
                    float sq = nv[0] * nv[0] + nv[1] * nv[1] + nv[2] * nv[2] + nv[3] * nv[3];
                    sq += __shfl_xor(sq, 1, 64);
                    sq += __shfl_xor(sq, 2, 64);
                    sq += __shfl_xor(sq, 4, 64);
                    sq += __shfl_xor(sq, 8, 64);
                    float rr = rsqrtf(sq * (1.0f / 64.0f) + 1e-6f);
                    if (head < H_) rr *= 0.125f;
                    #pragma unroll
                    for (int nt = 0; nt < 4; nt++) acc[mt][nt][r] = nv[nt] * rr;
                }
        }
    }

    #pragma unroll
    for (int mt = 0; mt < 2; mt++)
        #pragma unroll
        for (int nt = 0; nt < 4; nt++)
            #pragma unroll
            for (int r = 0; r < 4; r++) {
                size_t idx = (size_t)(m0 + wm + mt * 16 + quad * 4 + r) * Ni + n0 + nt * 16 + col;
                if constexpr (sizeof(T) == 2) Cm[idx] = f2bf(acc[mt][nt][r]);
                else                          Cm[idx] = acc[mt][nt][r];
            }
}

// ------------------------------------------------ V -> V^T global: vtb[(b*KV+kvh)][d][t]
__global__ __launch_bounds__(256) void vtrans_kernel(const unsigned short* __restrict__ qkvb,
                                                     unsigned short* __restrict__ vtb) {
    __shared__ unsigned short tileb[64][72];
    int tile = blockIdx.x & 31;
    int bkv  = blockIdx.x >> 5;
    int b = bkv >> 2, kvh = bkv & 3;
    int tid = threadIdx.x;
    int t0 = tile * 64;
    #pragma unroll
    for (int i = 0; i < 2; i++) {
        int idx = tid + i * 256;
        int r = idx >> 3, d8 = (idx & 7) * 8;
        *(uint4*)&tileb[r][d8] =
            *(const uint4*)&qkvb[(size_t)(b * T_ + t0 + r) * NQKV_ + 1280 + kvh * 64 + d8];
    }
    __syncthreads();
    #pragma unroll
    for (int i = 0; i < 2; i++) {
        int idx = tid + i * 256;
        int dr = idx >> 3, t8 = (idx & 7) * 8;
        unsigned short tmp[8];
        #pragma unroll
        for (int j = 0; j < 8; j++) tmp[j] = tileb[t8 + j][dr];
        *(uint4*)&vtb[((size_t)(bkv * 64 + dr)) * T_ + t0 + t8] = *(uint4*)tmp;
    }
}

// ------------------------------------------------ MFMA flash attention, 128-query tiles
// Q fragments in REGISTERS (loop-invariant) -> LDS = 54 KB -> 2 blocks/CU.
// block = (b, h, qt), qt descending; 4 waves; wave w owns q rows w*32..+31.
// K/V^T double-buffered via register prefetch, 1 barrier/iter.
__global__ __launch_bounds__(256) void attn_kernel(const unsigned short* __restrict__ qkvb,
                                                   const unsigned short* __restrict__ vtb,
                                                   unsigned short* __restrict__ yb) {
    __shared__ __align__(16) unsigned short Ks[2][64 * ST_];
    __shared__ __align__(16) unsigned short Vts[2][64 * ST_];
    __shared__ __align__(16) unsigned short Ps[128 * ST_];

    int bh = blockIdx.x & 31;
    int qt = 15 - (blockIdx.x >> 5);      // big blocks dispatch first
    int b = bh >> 4, h = bh & 15, kvh = h >> 2;
    int tid = threadIdx.x;
    int w = tid >> 6, lane = tid & 63;
    int col = lane & 15, quad = lane >> 4;
    int nkt = 2 * qt + 2;
    int tau0 = qt * 128;

    size_t kbase = (size_t)(b * T_) * NQKV_ + 1024 + kvh * 64;
    size_t vbase = (size_t)((b * KV_ + kvh) * 64) * T_;

    // K/V staging: row sr (0..63), cols sd, sd+32
    int sr = tid >> 2, sd = (tid & 3) * 8;

    // Q fragments straight from global into registers (A-layout):
    // lane (col, quad) holds Q[tau0 + w*32 + mt*16 + col][quad*8 + step*32 .. +8]
    bf16x8 aq[2][2];
    #pragma unroll
    for (int mt = 0; mt < 2; mt++)
        #pragma unroll
        for (int step = 0; step < 2; step++)
            aq[mt][step] = *(const bf16x8*)&qkvb[(size_t)(b * T_ + tau0 + w * 32 + mt * 16 + col) * NQKV_
                                                 + h * 64 + quad * 8 + step * 32];

    // preload + stage tile 0
    uint4 kreg[2], vreg[2];
    #pragma unroll
    for (int c = 0; c < 2; c++) {
        kreg[c] = *(const uint4*)&qkvb[kbase + (size_t)sr * NQKV_ + sd + c * 32];
        vreg[c] = *(const uint4*)&vtb[vbase + (size_t)sr * T_ + sd + c * 32];
    }
    #pragma unroll
    for (int c = 0; c < 2; c++) {
        *(uint4*)&Ks[0][sr * ST_ + sd + c * 32]  = kreg[c];
        *(uint4*)&Vts[0][sr * ST_ + sd + c * 32] = vreg[c];
    }
    __syncthreads();

    float mrow[2][4], lrow[2][4];
    #pragma unroll
    for (int mt = 0; mt < 2; mt++)
        #pragma unroll
        for (int r = 0; r < 4; r++) { mrow[mt][r] = -1e30f; lrow[mt][r] = 0.f; }
    f32x4 o[2][4];
    #pragma unroll
    for (int mt = 0; mt < 2; mt++)
        #pragma unroll
        for (int nt = 0; nt < 4; nt++) o[mt][nt] = (f32x4){0.f, 0.f, 0.f, 0.f};

    for (int kt = 0; kt < nkt; kt++) {
        int cur = kt & 1;
        if (kt + 1 < nkt) {
            #pragma unroll
            for (int c = 0; c < 2; c++) {
                kreg[c] = *(const uint4*)&qkvb[kbase + (size_t)((kt + 1) * 64 + sr) * NQKV_ + sd + c * 32];
                vreg[c] = *(const uint4*)&vtb[vbase + (size_t)sr * T_ + (kt + 1) * 64 + sd + c * 32];
            }
        }
        // S = Q K^T : 32q x 64k per wave
        f32x4 sacc[2][4];
        #pragma unroll
        for (int mt = 0; mt < 2; mt++)
            #pragma unroll
            for (int nt = 0; nt < 4; nt++) sacc[mt][nt] = (f32x4){0.f, 0.f, 0.f, 0.f};
        #pragma unroll
        for (int step = 0; step < 2; step++)
            #pragma unroll
            for (int nt = 0; nt < 4; nt++) {
                bf16x8 kb = *(const bf16x8*)&Ks[cur][(nt * 16 + col) * ST_ + quad * 8 + step * 32];
                #pragma unroll
                for (int mt = 0; mt < 2; mt++)
                    sacc[mt][nt] = __builtin_amdgcn_mfma_f32_16x16x32_bf16(aq[mt][step], kb, sacc[mt][nt], 0, 0, 0);
            }
        if (kt >= 2 * qt) {   // diagonal region: per-element causal mask
            #pragma unroll
            for (int mt = 0; mt < 2; mt++)
                #pragma unroll
                for (int nt = 0; nt < 4; nt++)
                    #pragma unroll
                    for (int r = 0; r < 4; r++)
                        if (kt * 64 + nt * 16 + col > tau0 + w * 32 + mt * 16 + quad * 4 + r)
                            sacc[mt][nt][r] = -1e30f;
        }
        // online softmax: lane owns 8 rows (mt, r); reduce across 16 col-lanes
        float alpha[2][4];
        #pragma unroll
        for (int mt = 0; mt < 2; mt++)
            #pragma unroll
            for (int r = 0; r < 4; r++) {
                float mx = fmaxf(fmaxf(sacc[mt][0][r], sacc[mt][1][r]), fmaxf(sacc[mt][2][r], sacc[mt][3][r]));
                mx = fmaxf(mx, __shfl_xor(mx, 1, 64));
                mx = fmaxf(mx, __shfl_xor(mx, 2, 64));
                mx = fmaxf(mx, __shfl_xor(mx, 4, 64));
                mx = fmaxf(mx, __shfl_xor(mx, 8, 64));
                float mnew = fmaxf(mrow[mt][r], mx);
                alpha[mt][r] = __expf(mrow[mt][r] - mnew);
                float rs = 0.f;
                #pragma unroll
                for (int nt = 0; nt < 4; nt++) {
                    float pv = __expf(sacc[mt][nt][r] - mnew);
                    sacc[mt][nt][r] = pv;
                    rs += pv;
                }
                rs += __shfl_xor(rs, 1, 64);
                rs += __shfl_xor(rs, 2, 64);
                rs += __shfl_xor(rs, 4, 64);
                rs += __shfl_xor(rs, 8, 64);
                lrow[mt][r] = lrow[mt][r] * alpha[mt][r] + rs;
                mrow[mt][r] = mnew;
            }
        // P -> LDS (wave-private stripe, no barrier needed before re-read)
        #pragma unroll
        for (int mt = 0; mt < 2; mt++)
            #pragma unroll
            for (int nt = 0; nt < 4; nt++)
                #pragma unroll
                for (int r = 0; r < 4; r++)
                    Ps[(w * 32 + mt * 16 + quad * 4 + r) * ST_ + nt * 16 + col] = f2bf(sacc[mt][nt][r]);
        #pragma unroll
        for (int mt = 0; mt < 2; mt++)
            #pragma unroll
            for (int nt = 0; nt < 4; nt++)
                #pragma unroll
                for (int r = 0; r < 4; r++)
                    o[mt][nt][r] *= alpha[mt][r];
        // O += P V
        #pragma unroll
        for (int step = 0; step < 2; step++) {
            bf16x8 ap[2];
            #pragma unroll
            for (int mt = 0; mt < 2; mt++)
                ap[mt] = *(const bf16x8*)&Ps[(w * 32 + mt * 16 + col) * ST_ + quad * 8 + step * 32];
            #pragma unroll
            for (int nt = 0; nt < 4; nt++) {
                bf16x8 vb = *(const bf16x8*)&Vts[cur][(nt * 16 + col) * ST_ + quad * 8 + step * 32];
                #pragma unroll
                for (int mt = 0; mt < 2; mt++)
                    o[mt][nt] = __builtin_amdgcn_mfma_f32_16x16x32_bf16(ap[mt], vb, o[mt][nt], 0, 0, 0);
            }
        }
        if (kt + 1 < nkt) {
            #pragma unroll
            for (int c = 0; c < 2; c++) {
                *(uint4*)&Ks[cur ^ 1][sr * ST_ + sd + c * 32]  = kreg[c];
                *(uint4*)&Vts[cur ^ 1][sr * ST_ + sd + c * 32] = vreg[c];
            }
        }
        __syncthreads();
    }

    #pragma unroll
    for (int mt = 0; mt < 2; mt++)
        #pragma unroll
        for (int r = 0; r < 4; r++) {
            float inv = 1.0f / lrow[mt][r];
            size_t row = (size_t)(b * T_ + tau0 + w * 32 + mt * 16 + quad * 4 + r) * C_ + h * 64;
            #pragma unroll
            for (int nt = 0; nt < 4; nt++)
                yb[row + nt * 16 + col] = f2bf(o[mt][nt][r] * inv);
        }
}

// ---------------------------------------------------------------- launch
extern "C" void kernel_launch(void* const* d_in, const int* in_sizes, int n_in,
                              void* d_out, int out_size, void* d_ws, size_t ws_size,
                              hipStream_t stream) {
    const float* x    = (const float*)d_in[0];
    const float* cosb = (const float*)d_in[1];
    const float* sinb = (const float*)d_in[2];
    const float* Wq   = (const float*)d_in[3];
    const float* Wk   = (const float*)d_in[4];
    const float* Wv   = (const float*)d_in[5];
    const float* Wo   = (const float*)d_in[6];
    float* out = (float*)d_out;

    char* ws = (char*)d_ws;
    unsigned short* xb    = (unsigned short*)(ws);               // 8 MB (reused as yb)
    unsigned short* yb    = (unsigned short*)(ws);               // alias: xb dead after QKV GEMM
    unsigned short* wtqkv = (unsigned short*)(ws + ( 8u << 20)); // 3 MB
    unsigned short* wto   = (unsigned short*)(ws + (11u << 20)); // 2 MB
    unsigned short* qkvb  = (unsigned short*)(ws + (13u << 20)); // 12 MB
    unsigned short* vtb   = (unsigned short*)(ws + (25u << 20)); // 2 MB

    cast_x_kernel<<<4096, 256, 0, stream>>>(x, xb);
    transpose4_kernel<<<2560, 256, 0, stream>>>(Wq, Wk, Wv, Wo, wtqkv, wto);
    // QKV projection + fused RoPE/RMSNorm -> bf16 qkv
    gemm_kernel<unsigned short, true><<<dim3(32, 24), 256, 0, stream>>>(xb, wtqkv, qkvb, NQKV_, cosb, sinb);
    vtrans_kernel<<<256, 256, 0, stream>>>(qkvb, vtb);
    attn_kernel<<<512, 256, 0, stream>>>(qkvb, vtb, yb);
    // output projection -> fp32 out
    gemm_kernel<float, false><<<dim3(32, 16), 256, 0, stream>>>(yb, wto, out, C_, nullptr, nullptr);
}

// Round 6
// 216.826 us; speedup vs baseline: 1.1781x; 1.1078x over previous
//
#include <hip/hip_runtime.h>
#include <hip/hip_bf16.h>

#define B_   2
#define T_   2048
#define C_   1024
#define H_   16
#define KV_  4
#define HD_  64
#define M_   (B_*T_)     // 4096 tokens
#define NQKV_ 1536       // 1024 q + 256 k + 256 v
#define ST_  72          // LDS row stride (bf16 elems): 144 B

typedef __bf16 bf16x8 __attribute__((ext_vector_type(8)));
typedef float  f32x4  __attribute__((ext_vector_type(4)));

static __device__ __forceinline__ unsigned short f2bf(float f) {
    __hip_bfloat16 h = __float2bfloat16(f);
    return __builtin_bit_cast(unsigned short, h);
}

// ---------------------------------------------------------------- cast x -> bf16
__global__ void cast_x_kernel(const float* __restrict__ x, unsigned short* __restrict__ xb) {
    int i = (blockIdx.x * 256 + threadIdx.x) * 4;
    float4 v = *(const float4*)(x + i);
    ushort4 o = make_ushort4(f2bf(v.x), f2bf(v.y), f2bf(v.z), f2bf(v.w));
    *(ushort4*)(xb + i) = o;
}

// --------------------------------------- all 4 weight transposes in one launch
__global__ void transpose4_kernel(const float* __restrict__ Wq, const float* __restrict__ Wk,
                                  const float* __restrict__ Wv, const float* __restrict__ Wo,
                                  unsigned short* __restrict__ wtqkv, unsigned short* __restrict__ wto) {
    __shared__ float tile[32][33];
    int bid = blockIdx.x;
    const float* src; unsigned short* dst; int s, nlog;
    if (bid < 1024)      { src = Wq; dst = wtqkv;               s = bid;        nlog = 5; }
    else if (bid < 1280) { src = Wk; dst = wtqkv + 1024 * 1024; s = bid - 1024; nlog = 3; }
    else if (bid < 1536) { src = Wv; dst = wtqkv + 1280 * 1024; s = bid - 1280; nlog = 3; }
    else                 { src = Wo; dst = wto;                 s = bid - 1536; nlog = 5; }
    int N  = 32 << nlog;
    int k0 = (s >> nlog) * 32, n0 = (s & ((1 << nlog) - 1)) * 32;
    int lr = threadIdx.x >> 5, lc = threadIdx.x & 31;
    #pragma unroll
    for (int i = 0; i < 4; i++) {
        int r = lr + i * 8;
        tile[r][lc] = src[(k0 + r) * N + n0 + lc];
    }
    __syncthreads();
    #pragma unroll
    for (int i = 0; i < 4; i++) {
        int r = lr + i * 8;
        dst[(n0 + r) * 1024 + k0 + lc] = f2bf(tile[lc][r]);
    }
}

// ------------------------------------------------ 128x64 bf16 MFMA GEMM, K=1024, BK=32
// ROPE=true: fused RoPE+RMSNorm epilogue (heads 0..15 q *0.125, 16..19 k, 20..23 v pass).
template <typename T, bool ROPE>
__global__ __launch_bounds__(256) void gemm_kernel(const unsigned short* __restrict__ A,
                                                   const unsigned short* __restrict__ Bt,
                                                   T* __restrict__ Cm, int Ni,
                                                   const float* __restrict__ cosb,
                                                   const float* __restrict__ sinb) {
    __shared__ __align__(16) unsigned short As[128 * 32];
    __shared__ __align__(16) unsigned short Bs[64 * 32];
    int m0 = blockIdx.x * 128;
    int head = blockIdx.y;
    int n0 = head * 64;
    int tid = threadIdx.x;
    int w = tid >> 6, lane = tid & 63;
    int col = lane & 15, quad = lane >> 4;
    int wm = w * 32;
    int ar = tid >> 2, ak = (tid & 3) * 8;

    f32x4 acc[2][4];
    #pragma unroll
    for (int mt = 0; mt < 2; mt++)
        #pragma unroll
        for (int nt = 0; nt < 4; nt++) acc[mt][nt] = (f32x4){0.f, 0.f, 0.f, 0.f};

    for (int k0 = 0; k0 < 1024; k0 += 32) {
        __builtin_amdgcn_global_load_lds(
            (const __attribute__((address_space(1))) unsigned int*)(A + (size_t)(m0 + ar) * 1024 + k0 + ak),
            (__attribute__((address_space(3))) unsigned int*)(As + ar * 32 + ak), 16, 0, 0);
        __builtin_amdgcn_global_load_lds(
            (const __attribute__((address_space(1))) unsigned int*)(A + (size_t)(m0 + ar + 64) * 1024 + k0 + ak),
            (__attribute__((address_space(3))) unsigned int*)(As + (ar + 64) * 32 + ak), 16, 0, 0);
        __builtin_amdgcn_global_load_lds(
            (const __attribute__((address_space(1))) unsigned int*)(Bt + (size_t)(n0 + ar) * 1024 + k0 + ak),
            (__attribute__((address_space(3))) unsigned int*)(Bs + ar * 32 + ak), 16, 0, 0);
        __syncthreads();
        bf16x8 af[2], bfr[4];
        #pragma unroll
        for (int mt = 0; mt < 2; mt++) af[mt]  = *(const bf16x8*)&As[(wm + mt * 16 + col) * 32 + quad * 8];
        #pragma unroll
        for (int nt = 0; nt < 4; nt++) bfr[nt] = *(const bf16x8*)&Bs[(nt * 16 + col) * 32 + quad * 8];
        #pragma unroll
        for (int mt = 0; mt < 2; mt++)
            #pragma unroll
            for (int nt = 0; nt < 4; nt++)
                acc[mt][nt] = __builtin_amdgcn_mfma_f32_16x16x32_bf16(af[mt], bfr[nt], acc[mt][nt], 0, 0, 0);
        __syncthreads();
    }

    if constexpr (ROPE) {
        if (head < H_ + KV_) {
            #pragma unroll
            for (int mt = 0; mt < 2; mt++)
                #pragma unroll
                for (int r = 0; r < 4; r++) {
                    int t = (m0 + wm + mt * 16 + quad * 4 + r) & (T_ - 1);
                    float nv[4];
                    #pragma unroll
                    for (int nt = 0; nt < 4; nt++) {
                        int i = (nt & 1) * 16 + col;
                        float c = cosb[t * 32 + i], s = sinb[t * 32 + i];
                        float v = acc[mt][nt][r], p = acc[mt][nt ^ 2][r];
                        nv[nt] = (nt < 2) ? (v * c + p * s) : (v * c - p * s);
                    }
                    float sq = nv[0] * nv[0] + nv[1] * nv[1] + nv[2] * nv[2] + nv[3] * nv[3];
                    sq += __shfl_xor(sq, 1, 64);
                    sq += __shfl_xor(sq, 2, 64);
                    sq += __shfl_xor(sq, 4, 64);
                    sq += __shfl_xor(sq, 8, 64);
                    float rr = rsqrtf(sq * (1.0f / 64.0f) + 1e-6f);
                    if (head < H_) rr *= 0.125f;
                    #pragma unroll
                    for (int nt = 0; nt < 4; nt++) acc[mt][nt][r] = nv[nt] * rr;
                }
        }
    }

    #pragma unroll
    for (int mt = 0; mt < 2; mt++)
        #pragma unroll
        for (int nt = 0; nt < 4; nt++)
            #pragma unroll
            for (int r = 0; r < 4; r++) {
                size_t idx = (size_t)(m0 + wm + mt * 16 + quad * 4 + r) * Ni + n0 + nt * 16 + col;
                if constexpr (sizeof(T) == 2) Cm[idx] = f2bf(acc[mt][nt][r]);
                else                          Cm[idx] = acc[mt][nt][r];
            }
}

// ------------------------------------------------ V -> V^T global: vtb[(b*KV+kvh)][d][t]
__global__ __launch_bounds__(256) void vtrans_kernel(const unsigned short* __restrict__ qkvb,
                                                     unsigned short* __restrict__ vtb) {
    __shared__ unsigned short tileb[64][72];
    int tile = blockIdx.x & 31;
    int bkv  = blockIdx.x >> 5;
    int b = bkv >> 2, kvh = bkv & 3;
    int tid = threadIdx.x;
    int t0 = tile * 64;
    #pragma unroll
    for (int i = 0; i < 2; i++) {
        int idx = tid + i * 256;
        int r = idx >> 3, d8 = (idx & 7) * 8;
        *(uint4*)&tileb[r][d8] =
            *(const uint4*)&qkvb[(size_t)(b * T_ + t0 + r) * NQKV_ + 1280 + kvh * 64 + d8];
    }
    __syncthreads();
    #pragma unroll
    for (int i = 0; i < 2; i++) {
        int idx = tid + i * 256;
        int dr = idx >> 3, t8 = (idx & 7) * 8;
        unsigned short tmp[8];
        #pragma unroll
        for (int j = 0; j < 8; j++) tmp[j] = tileb[t8 + j][dr];
        *(uint4*)&vtb[((size_t)(bkv * 64 + dr)) * T_ + t0 + t8] = *(uint4*)tmp;
    }
}

// ------------------------------------------------ MFMA flash attention, 128-query tiles
// FIXED-MAX softmax: q,k are RMS-normalized (|q'| <= 1 after 0.125 scale, |k| <= 8),
// so s in [-8,8] by Cauchy-Schwarz -> p = exp(s-8) <= 1, l <= 2048. No running max,
// no shuffles, no rescale. l accumulated via MFMA ones-trick (B = splat 1.0bf16).
// Q frags in registers; K/V^T double-buffered via register prefetch, 1 barrier/iter.
__global__ __launch_bounds__(256) void attn_kernel(const unsigned short* __restrict__ qkvb,
                                                   const unsigned short* __restrict__ vtb,
                                                   unsigned short* __restrict__ yb) {
    __shared__ __align__(16) unsigned short Ks[2][64 * ST_];
    __shared__ __align__(16) unsigned short Vts[2][64 * ST_];
    __shared__ __align__(16) unsigned short Ps[128 * ST_];

    int bh = blockIdx.x & 31;
    int qt = 15 - (blockIdx.x >> 5);      // big blocks dispatch first
    int b = bh >> 4, h = bh & 15, kvh = h >> 2;
    int tid = threadIdx.x;
    int w = tid >> 6, lane = tid & 63;
    int col = lane & 15, quad = lane >> 4;
    int nkt = 2 * qt + 2;
    int tau0 = qt * 128;

    size_t kbase = (size_t)(b * T_) * NQKV_ + 1024 + kvh * 64;
    size_t vbase = (size_t)((b * KV_ + kvh) * 64) * T_;

    // K/V staging: row sr (0..63), cols sd, sd+32
    int sr = tid >> 2, sd = (tid & 3) * 8;

    // Q fragments straight from global into registers (A-layout)
    bf16x8 aq[2][2];
    #pragma unroll
    for (int mt = 0; mt < 2; mt++)
        #pragma unroll
        for (int step = 0; step < 2; step++)
            aq[mt][step] = *(const bf16x8*)&qkvb[(size_t)(b * T_ + tau0 + w * 32 + mt * 16 + col) * NQKV_
                                                 + h * 64 + quad * 8 + step * 32];

    // ones B-fragment for the l row-sum MFMA
    bf16x8 ones;
    #pragma unroll
    for (int j = 0; j < 8; j++) ones[j] = (__bf16)1.0f;

    // preload + stage tile 0
    uint4 kreg[2], vreg[2];
    #pragma unroll
    for (int c = 0; c < 2; c++) {
        kreg[c] = *(const uint4*)&qkvb[kbase + (size_t)sr * NQKV_ + sd + c * 32];
        vreg[c] = *(const uint4*)&vtb[vbase + (size_t)sr * T_ + sd + c * 32];
    }
    #pragma unroll
    for (int c = 0; c < 2; c++) {
        *(uint4*)&Ks[0][sr * ST_ + sd + c * 32]  = kreg[c];
        *(uint4*)&Vts[0][sr * ST_ + sd + c * 32] = vreg[c];
    }
    __syncthreads();

    f32x4 o[2][4], lacc[2];
    #pragma unroll
    for (int mt = 0; mt < 2; mt++) {
        lacc[mt] = (f32x4){0.f, 0.f, 0.f, 0.f};
        #pragma unroll
        for (int nt = 0; nt < 4; nt++) o[mt][nt] = (f32x4){0.f, 0.f, 0.f, 0.f};
    }

    for (int kt = 0; kt < nkt; kt++) {
        int cur = kt & 1;
        if (kt + 1 < nkt) {
            #pragma unroll
            for (int c = 0; c < 2; c++) {
                kreg[c] = *(const uint4*)&qkvb[kbase + (size_t)((kt + 1) * 64 + sr) * NQKV_ + sd + c * 32];
                vreg[c] = *(const uint4*)&vtb[vbase + (size_t)sr * T_ + (kt + 1) * 64 + sd + c * 32];
            }
        }
        // S = Q K^T : 32q x 64k per wave
        f32x4 sacc[2][4];
        #pragma unroll
        for (int mt = 0; mt < 2; mt++)
            #pragma unroll
            for (int nt = 0; nt < 4; nt++) sacc[mt][nt] = (f32x4){0.f, 0.f, 0.f, 0.f};
        #pragma unroll
        for (int step = 0; step < 2; step++)
            #pragma unroll
            for (int nt = 0; nt < 4; nt++) {
                bf16x8 kb = *(const bf16x8*)&Ks[cur][(nt * 16 + col) * ST_ + quad * 8 + step * 32];
                #pragma unroll
                for (int mt = 0; mt < 2; mt++)
                    sacc[mt][nt] = __builtin_amdgcn_mfma_f32_16x16x32_bf16(aq[mt][step], kb, sacc[mt][nt], 0, 0, 0);
            }
        if (kt >= 2 * qt) {   // diagonal region: per-element causal mask
            #pragma unroll
            for (int mt = 0; mt < 2; mt++)
                #pragma unroll
                for (int nt = 0; nt < 4; nt++)
                    #pragma unroll
                    for (int r = 0; r < 4; r++)
                        if (kt * 64 + nt * 16 + col > tau0 + w * 32 + mt * 16 + quad * 4 + r)
                            sacc[mt][nt][r] = -1e30f;
        }
        // fixed-max softmax: p = exp(s - 8), write straight to LDS (wave-private stripe)
        #pragma unroll
        for (int mt = 0; mt < 2; mt++)
            #pragma unroll
            for (int nt = 0; nt < 4; nt++)
                #pragma unroll
                for (int r = 0; r < 4; r++)
                    Ps[(w * 32 + mt * 16 + quad * 4 + r) * ST_ + nt * 16 + col] =
                        f2bf(__expf(sacc[mt][nt][r] - 8.0f));
        // O += P V ; l += P * ones
        #pragma unroll
        for (int step = 0; step < 2; step++) {
            bf16x8 ap[2];
            #pragma unroll
            for (int mt = 0; mt < 2; mt++)
                ap[mt] = *(const bf16x8*)&Ps[(w * 32 + mt * 16 + col) * ST_ + quad * 8 + step * 32];
            #pragma unroll
            for (int nt = 0; nt < 4; nt++) {
                bf16x8 vb = *(const bf16x8*)&Vts[cur][(nt * 16 + col) * ST_ + quad * 8 + step * 32];
                #pragma unroll
                for (int mt = 0; mt < 2; mt++)
                    o[mt][nt] = __builtin_amdgcn_mfma_f32_16x16x32_bf16(ap[mt], vb, o[mt][nt], 0, 0, 0);
            }
            #pragma unroll
            for (int mt = 0; mt < 2; mt++)
                lacc[mt] = __builtin_amdgcn_mfma_f32_16x16x32_bf16(ap[mt], ones, lacc[mt], 0, 0, 0);
        }
        if (kt + 1 < nkt) {
            #pragma unroll
            for (int c = 0; c < 2; c++) {
                *(uint4*)&Ks[cur ^ 1][sr * ST_ + sd + c * 32]  = kreg[c];
                *(uint4*)&Vts[cur ^ 1][sr * ST_ + sd + c * 32] = vreg[c];
            }
        }
        __syncthreads();
    }

    #pragma unroll
    for (int mt = 0; mt < 2; mt++)
        #pragma unroll
        for (int r = 0; r < 4; r++) {
            float inv = 1.0f / lacc[mt][r];
            size_t row = (size_t)(b * T_ + tau0 + w * 32 + mt * 16 + quad * 4 + r) * C_ + h * 64;
            #pragma unroll
            for (int nt = 0; nt < 4; nt++)
                yb[row + nt * 16 + col] = f2bf(o[mt][nt][r] * inv);
        }
}

// ---------------------------------------------------------------- launch
extern "C" void kernel_launch(void* const* d_in, const int* in_sizes, int n_in,
                              void* d_out, int out_size, void* d_ws, size_t ws_size,
                              hipStream_t stream) {
    const float* x    = (const float*)d_in[0];
    const float* cosb = (const float*)d_in[1];
    const float* sinb = (const float*)d_in[2];
    const float* Wq   = (const float*)d_in[3];
    const float* Wk   = (const float*)d_in[4];
    const float* Wv   = (const float*)d_in[5];
    const float* Wo   = (const float*)d_in[6];
    float* out = (float*)d_out;

    char* ws = (char*)d_ws;
    unsigned short* xb    = (unsigned short*)(ws);               // 8 MB (reused as yb)
    unsigned short* yb    = (unsigned short*)(ws);               // alias: xb dead after QKV GEMM
    unsigned short* wtqkv = (unsigned short*)(ws + ( 8u << 20)); // 3 MB
    unsigned short* wto   = (unsigned short*)(ws + (11u << 20)); // 2 MB
    unsigned short* qkvb  = (unsigned short*)(ws + (13u << 20)); // 12 MB
    unsigned short* vtb   = (unsigned short*)(ws + (25u << 20)); // 2 MB

    cast_x_kernel<<<4096, 256, 0, stream>>>(x, xb);
    transpose4_kernel<<<2560, 256, 0, stream>>>(Wq, Wk, Wv, Wo, wtqkv, wto);
    // QKV projection + fused RoPE/RMSNorm -> bf16 qkv
    gemm_kernel<unsigned short, true><<<dim3(32, 24), 256, 0, stream>>>(xb, wtqkv, qkvb, NQKV_, cosb, sinb);
    vtrans_kernel<<<256, 256, 0, stream>>>(qkvb, vtb);
    attn_kernel<<<512, 256, 0, stream>>>(qkvb, vtb, yb);
    // output projection -> fp32 out
    gemm_kernel<float, false><<<dim3(32, 16), 256, 0, stream>>>(yb, wto, out, C_, nullptr, nullptr);
}

// Round 7
// 202.316 us; speedup vs baseline: 1.2625x; 1.0717x over previous
//
#include <hip/hip_runtime.h>
#include <hip/hip_bf16.h>

#define B_   2
#define T_   2048
#define C_   1024
#define H_   16
#define KV_  4
#define HD_  64
#define M_   (B_*T_)     // 4096 tokens
#define NQKV_ 1536       // 1024 q + 256 k + 256 v
#define PST_ 72          // P LDS row stride (bf16): 144 B = 9*16 B (b128-aligned)

typedef __bf16 bf16x8 __attribute__((ext_vector_type(8)));
typedef float  f32x4  __attribute__((ext_vector_type(4)));

static __device__ __forceinline__ unsigned short f2bf(float f) {
    __hip_bfloat16 h = __float2bfloat16(f);
    return __builtin_bit_cast(unsigned short, h);
}

// ---------------------------------------------------------------- cast x -> bf16
__global__ void cast_x_kernel(const float* __restrict__ x, unsigned short* __restrict__ xb) {
    int i = (blockIdx.x * 256 + threadIdx.x) * 4;
    float4 v = *(const float4*)(x + i);
    ushort4 o = make_ushort4(f2bf(v.x), f2bf(v.y), f2bf(v.z), f2bf(v.w));
    *(ushort4*)(xb + i) = o;
}

// --------------------------------------- all 4 weight transposes in one launch
__global__ void transpose4_kernel(const float* __restrict__ Wq, const float* __restrict__ Wk,
                                  const float* __restrict__ Wv, const float* __restrict__ Wo,
                                  unsigned short* __restrict__ wtqkv, unsigned short* __restrict__ wto) {
    __shared__ float tile[32][33];
    int bid = blockIdx.x;
    const float* src; unsigned short* dst; int s, nlog;
    if (bid < 1024)      { src = Wq; dst = wtqkv;               s = bid;        nlog = 5; }
    else if (bid < 1280) { src = Wk; dst = wtqkv + 1024 * 1024; s = bid - 1024; nlog = 3; }
    else if (bid < 1536) { src = Wv; dst = wtqkv + 1280 * 1024; s = bid - 1280; nlog = 3; }
    else                 { src = Wo; dst = wto;                 s = bid - 1536; nlog = 5; }
    int N  = 32 << nlog;
    int k0 = (s >> nlog) * 32, n0 = (s & ((1 << nlog) - 1)) * 32;
    int lr = threadIdx.x >> 5, lc = threadIdx.x & 31;
    #pragma unroll
    for (int i = 0; i < 4; i++) {
        int r = lr + i * 8;
        tile[r][lc] = src[(k0 + r) * N + n0 + lc];
    }
    __syncthreads();
    #pragma unroll
    for (int i = 0; i < 4; i++) {
        int r = lr + i * 8;
        dst[(n0 + r) * 1024 + k0 + lc] = f2bf(tile[lc][r]);
    }
}

// ------------------------------------------------ 128x64 bf16 MFMA GEMM, K=1024, BK=32
// ROPE=true: fused RoPE+RMSNorm epilogue (heads 0..15 q *0.125, 16..19 k, 20..23 v pass).
template <typename T, bool ROPE>
__global__ __launch_bounds__(256) void gemm_kernel(const unsigned short* __restrict__ A,
                                                   const unsigned short* __restrict__ Bt,
                                                   T* __restrict__ Cm, int Ni,
                                                   const float* __restrict__ cosb,
                                                   const float* __restrict__ sinb) {
    __shared__ __align__(16) unsigned short As[128 * 32];
    __shared__ __align__(16) unsigned short Bs[64 * 32];
    int m0 = blockIdx.x * 128;
    int head = blockIdx.y;
    int n0 = head * 64;
    int tid = threadIdx.x;
    int w = tid >> 6, lane = tid & 63;
    int col = lane & 15, quad = lane >> 4;
    int wm = w * 32;
    int ar = tid >> 2, ak = (tid & 3) * 8;

    f32x4 acc[2][4];
    #pragma unroll
    for (int mt = 0; mt < 2; mt++)
        #pragma unroll
        for (int nt = 0; nt < 4; nt++) acc[mt][nt] = (f32x4){0.f, 0.f, 0.f, 0.f};

    for (int k0 = 0; k0 < 1024; k0 += 32) {
        __builtin_amdgcn_global_load_lds(
            (const __attribute__((address_space(1))) unsigned int*)(A + (size_t)(m0 + ar) * 1024 + k0 + ak),
            (__attribute__((address_space(3))) unsigned int*)(As + ar * 32 + ak), 16, 0, 0);
        __builtin_amdgcn_global_load_lds(
            (const __attribute__((address_space(1))) unsigned int*)(A + (size_t)(m0 + ar + 64) * 1024 + k0 + ak),
            (__attribute__((address_space(3))) unsigned int*)(As + (ar + 64) * 32 + ak), 16, 0, 0);
        __builtin_amdgcn_global_load_lds(
            (const __attribute__((address_space(1))) unsigned int*)(Bt + (size_t)(n0 + ar) * 1024 + k0 + ak),
            (__attribute__((address_space(3))) unsigned int*)(Bs + ar * 32 + ak), 16, 0, 0);
        __syncthreads();
        bf16x8 af[2], bfr[4];
        #pragma unroll
        for (int mt = 0; mt < 2; mt++) af[mt]  = *(const bf16x8*)&As[(wm + mt * 16 + col) * 32 + quad * 8];
        #pragma unroll
        for (int nt = 0; nt < 4; nt++) bfr[nt] = *(const bf16x8*)&Bs[(nt * 16 + col) * 32 + quad * 8];
        #pragma unroll
        for (int mt = 0; mt < 2; mt++)
            #pragma unroll
            for (int nt = 0; nt < 4; nt++)
                acc[mt][nt] = __builtin_amdgcn_mfma_f32_16x16x32_bf16(af[mt], bfr[nt], acc[mt][nt], 0, 0, 0);
        __syncthreads();
    }

    if constexpr (ROPE) {
        if (head < H_ + KV_) {
            #pragma unroll
            for (int mt = 0; mt < 2; mt++)
                #pragma unroll
                for (int r = 0; r < 4; r++) {
                    int t = (m0 + wm + mt * 16 + quad * 4 + r) & (T_ - 1);
                    float nv[4];
                    #pragma unroll
                    for (int nt = 0; nt < 4; nt++) {
                        int i = (nt & 1) * 16 + col;
                        float c = cosb[t * 32 + i], s = sinb[t * 32 + i];
                        float v = acc[mt][nt][r], p = acc[mt][nt ^ 2][r];
                        nv[nt] = (nt < 2) ? (v * c + p * s) : (v * c - p * s);
                    }
                    float sq = nv[0] * nv[0] + nv[1] * nv[1] + nv[2] * nv[2] + nv[3] * nv[3];
                    sq += __shfl_xor(sq, 1, 64);
                    sq += __shfl_xor(sq, 2, 64);
                    sq += __shfl_xor(sq, 4, 64);
                    sq += __shfl_xor(sq, 8, 64);
                    float rr = rsqrtf(sq * (1.0f / 64.0f) + 1e-6f);
                    if (head < H_) rr *= 0.125f;
                    #pragma unroll
                    for (int nt = 0; nt < 4; nt++) acc[mt][nt][r] = nv[nt] * rr;
                }
        }
    }

    #pragma unroll
    for (int mt = 0; mt < 2; mt++)
        #pragma unroll
        for (int nt = 0; nt < 4; nt++)
            #pragma unroll
            for (int r = 0; r < 4; r++) {
                size_t idx = (size_t)(m0 + wm + mt * 16 + quad * 4 + r) * Ni + n0 + nt * 16 + col;
                if constexpr (sizeof(T) == 2) Cm[idx] = f2bf(acc[mt][nt][r]);
                else                          Cm[idx] = acc[mt][nt][r];
            }
}

// ------------------------------------------------ V -> V^T global: vtb[(b*KV+kvh)][d][t]
__global__ __launch_bounds__(256) void vtrans_kernel(const unsigned short* __restrict__ qkvb,
                                                     unsigned short* __restrict__ vtb) {
    __shared__ unsigned short tileb[64][72];
    int tile = blockIdx.x & 31;
    int bkv  = blockIdx.x >> 5;
    int b = bkv >> 2, kvh = bkv & 3;
    int tid = threadIdx.x;
    int t0 = tile * 64;
    #pragma unroll
    for (int i = 0; i < 2; i++) {
        int idx = tid + i * 256;
        int r = idx >> 3, d8 = (idx & 7) * 8;
        *(uint4*)&tileb[r][d8] =
            *(const uint4*)&qkvb[(size_t)(b * T_ + t0 + r) * NQKV_ + 1280 + kvh * 64 + d8];
    }
    __syncthreads();
    #pragma unroll
    for (int i = 0; i < 2; i++) {
        int idx = tid + i * 256;
        int dr = idx >> 3, t8 = (idx & 7) * 8;
        unsigned short tmp[8];
        #pragma unroll
        for (int j = 0; j < 8; j++) tmp[j] = tileb[t8 + j][dr];
        *(uint4*)&vtb[((size_t)(bkv * 64 + dr)) * T_ + t0 + t8] = *(uint4*)tmp;
    }
}

// ------------------------------------------------ MFMA flash attention: ONE WAVE PER BLOCK
// wave = 32 q-rows of one (b,h); K/V B-frags loaded DIRECTLY from global (L2-resident,
// KV total 3 MB); LDS only holds the wave-private P tile (no barriers anywhere).
// Fixed-max softmax (s in [-8,8] since q,k RMS-normalized): p=exp(s-8), l via ones-MFMA.
__global__ __launch_bounds__(64) void attn_kernel(const unsigned short* __restrict__ qkvb,
                                                  const unsigned short* __restrict__ vtb,
                                                  unsigned short* __restrict__ yb) {
    __shared__ __align__(16) unsigned short Ps[32 * PST_];   // 4.5 KB, wave-private

    int bh = blockIdx.x & 31;
    int qt = 63 - (blockIdx.x >> 5);        // 0..63, big tiles dispatch first
    int b = bh >> 4, h = bh & 15, kvh = h >> 2;
    int lane = threadIdx.x;
    int col = lane & 15, quad = lane >> 4;
    int t0 = qt * 32;
    int nkt = (t0 + 32 + 63) >> 6;          // 64-key tiles to cover keys <= t0+31

    const unsigned short* kptr = qkvb + (size_t)(b * T_) * NQKV_ + 1024 + kvh * 64;
    const unsigned short* vptr = vtb + (size_t)((b * KV_ + kvh) * 64) * T_;

    // Q A-frags (loop-invariant, registers)
    bf16x8 aq[2][2];
    #pragma unroll
    for (int mt = 0; mt < 2; mt++)
        #pragma unroll
        for (int step = 0; step < 2; step++)
            aq[mt][step] = *(const bf16x8*)&qkvb[(size_t)(b * T_ + t0 + mt * 16 + col) * NQKV_
                                                 + h * 64 + quad * 8 + step * 32];
    bf16x8 ones;
    #pragma unroll
    for (int j = 0; j < 8; j++) ones[j] = (__bf16)1.0f;

    f32x4 o[2][4], lacc[2];
    #pragma unroll
    for (int mt = 0; mt < 2; mt++) {
        lacc[mt] = (f32x4){0.f, 0.f, 0.f, 0.f};
        #pragma unroll
        for (int nt = 0; nt < 4; nt++) o[mt][nt] = (f32x4){0.f, 0.f, 0.f, 0.f};
    }

    for (int kt = 0; kt < nkt; kt++) {
        // S = Q K^T; K B-frags straight from global (per-step to cap liveness)
        f32x4 sacc[2][4];
        #pragma unroll
        for (int mt = 0; mt < 2; mt++)
            #pragma unroll
            for (int nt = 0; nt < 4; nt++) sacc[mt][nt] = (f32x4){0.f, 0.f, 0.f, 0.f};
        #pragma unroll
        for (int step = 0; step < 2; step++) {
            bf16x8 kb[4];
            #pragma unroll
            for (int nt = 0; nt < 4; nt++)
                kb[nt] = *(const bf16x8*)&kptr[(size_t)(kt * 64 + nt * 16 + col) * NQKV_
                                               + quad * 8 + step * 32];
            #pragma unroll
            for (int nt = 0; nt < 4; nt++)
                #pragma unroll
                for (int mt = 0; mt < 2; mt++)
                    sacc[mt][nt] = __builtin_amdgcn_mfma_f32_16x16x32_bf16(aq[mt][step], kb[nt], sacc[mt][nt], 0, 0, 0);
        }
        // issue V B-frag loads now; latency hides under exp/pack below
        bf16x8 vb[2][4];
        #pragma unroll
        for (int step = 0; step < 2; step++)
            #pragma unroll
            for (int nt = 0; nt < 4; nt++)
                vb[step][nt] = *(const bf16x8*)&vptr[(size_t)(nt * 16 + col) * T_
                                                     + kt * 64 + quad * 8 + step * 32];
        if (kt == nkt - 1) {   // diagonal: causal mask
            #pragma unroll
            for (int mt = 0; mt < 2; mt++)
                #pragma unroll
                for (int nt = 0; nt < 4; nt++)
                    #pragma unroll
                    for (int r = 0; r < 4; r++)
                        if (kt * 64 + nt * 16 + col > t0 + mt * 16 + quad * 4 + r)
                            sacc[mt][nt][r] = -1e30f;
        }
        // p = exp(s - 8) -> P tile in LDS (C-layout write, A-layout read; same wave, no barrier)
        #pragma unroll
        for (int mt = 0; mt < 2; mt++)
            #pragma unroll
            for (int nt = 0; nt < 4; nt++)
                #pragma unroll
                for (int r = 0; r < 4; r++)
                    Ps[(mt * 16 + quad * 4 + r) * PST_ + nt * 16 + col] =
                        f2bf(__expf(sacc[mt][nt][r] - 8.0f));
        // O += P V ; l += P * ones
        #pragma unroll
        for (int step = 0; step < 2; step++) {
            bf16x8 ap[2];
            #pragma unroll
            for (int mt = 0; mt < 2; mt++)
                ap[mt] = *(const bf16x8*)&Ps[(mt * 16 + col) * PST_ + quad * 8 + step * 32];
            #pragma unroll
            for (int nt = 0; nt < 4; nt++)
                #pragma unroll
                for (int mt = 0; mt < 2; mt++)
                    o[mt][nt] = __builtin_amdgcn_mfma_f32_16x16x32_bf16(ap[mt], vb[step][nt], o[mt][nt], 0, 0, 0);
            #pragma unroll
            for (int mt = 0; mt < 2; mt++)
                lacc[mt] = __builtin_amdgcn_mfma_f32_16x16x32_bf16(ap[mt], ones, lacc[mt], 0, 0, 0);
        }
    }

    #pragma unroll
    for (int mt = 0; mt < 2; mt++)
        #pragma unroll
        for (int r = 0; r < 4; r++) {
            float inv = 1.0f / lacc[mt][r];
            size_t row = (size_t)(b * T_ + t0 + mt * 16 + quad * 4 + r) * C_ + h * 64;
            #pragma unroll
            for (int nt = 0; nt < 4; nt++)
                yb[row + nt * 16 + col] = f2bf(o[mt][nt][r] * inv);
        }
}

// ---------------------------------------------------------------- launch
extern "C" void kernel_launch(void* const* d_in, const int* in_sizes, int n_in,
                              void* d_out, int out_size, void* d_ws, size_t ws_size,
                              hipStream_t stream) {
    const float* x    = (const float*)d_in[0];
    const float* cosb = (const float*)d_in[1];
    const float* sinb = (const float*)d_in[2];
    const float* Wq   = (const float*)d_in[3];
    const float* Wk   = (const float*)d_in[4];
    const float* Wv   = (const float*)d_in[5];
    const float* Wo   = (const float*)d_in[6];
    float* out = (float*)d_out;

    char* ws = (char*)d_ws;
    unsigned short* xb    = (unsigned short*)(ws);               // 8 MB (reused as yb)
    unsigned short* yb    = (unsigned short*)(ws);               // alias: xb dead after QKV GEMM
    unsigned short* wtqkv = (unsigned short*)(ws + ( 8u << 20)); // 3 MB
    unsigned short* wto   = (unsigned short*)(ws + (11u << 20)); // 2 MB
    unsigned short* qkvb  = (unsigned short*)(ws + (13u << 20)); // 12 MB
    unsigned short* vtb   = (unsigned short*)(ws + (25u << 20)); // 2 MB

    cast_x_kernel<<<4096, 256, 0, stream>>>(x, xb);
    transpose4_kernel<<<2560, 256, 0, stream>>>(Wq, Wk, Wv, Wo, wtqkv, wto);
    // QKV projection + fused RoPE/RMSNorm -> bf16 qkv
    gemm_kernel<unsigned short, true><<<dim3(32, 24), 256, 0, stream>>>(xb, wtqkv, qkvb, NQKV_, cosb, sinb);
    vtrans_kernel<<<256, 256, 0, stream>>>(qkvb, vtb);
    // barrier-free single-wave flash attention -> yb (bf16)
    attn_kernel<<<2048, 64, 0, stream>>>(qkvb, vtb, yb);
    // output projection -> fp32 out
    gemm_kernel<float, false><<<dim3(32, 16), 256, 0, stream>>>(yb, wto, out, C_, nullptr, nullptr);
}

// Round 8
// 195.969 us; speedup vs baseline: 1.3034x; 1.0324x over previous
//
#include <hip/hip_runtime.h>
#include <hip/hip_bf16.h>

#define B_   2
#define T_   2048
#define C_   1024
#define H_   16
#define KV_  4
#define HD_  64
#define M_   (B_*T_)     // 4096 tokens
#define NQKV_ 1536       // 1024 q + 256 k + 256 v
#define PST_ 72          // P LDS row stride (bf16): 144 B

typedef __bf16 bf16x8 __attribute__((ext_vector_type(8)));
typedef float  f32x4  __attribute__((ext_vector_type(4)));

static __device__ __forceinline__ unsigned short f2bf(float f) {
    __hip_bfloat16 h = __float2bfloat16(f);
    return __builtin_bit_cast(unsigned short, h);
}

// ---------------------------------------------------------------- cast x -> bf16
__global__ void cast_x_kernel(const float* __restrict__ x, unsigned short* __restrict__ xb) {
    int i = (blockIdx.x * 256 + threadIdx.x) * 4;
    float4 v = *(const float4*)(x + i);
    ushort4 o = make_ushort4(f2bf(v.x), f2bf(v.y), f2bf(v.z), f2bf(v.w));
    *(ushort4*)(xb + i) = o;
}

// --------------------------------------- all 4 weight transposes in one launch
__global__ void transpose4_kernel(const float* __restrict__ Wq, const float* __restrict__ Wk,
                                  const float* __restrict__ Wv, const float* __restrict__ Wo,
                                  unsigned short* __restrict__ wtqkv, unsigned short* __restrict__ wto) {
    __shared__ float tile[32][33];
    int bid = blockIdx.x;
    const float* src; unsigned short* dst; int s, nlog;
    if (bid < 1024)      { src = Wq; dst = wtqkv;               s = bid;        nlog = 5; }
    else if (bid < 1280) { src = Wk; dst = wtqkv + 1024 * 1024; s = bid - 1024; nlog = 3; }
    else if (bid < 1536) { src = Wv; dst = wtqkv + 1280 * 1024; s = bid - 1280; nlog = 3; }
    else                 { src = Wo; dst = wto;                 s = bid - 1536; nlog = 5; }
    int N  = 32 << nlog;
    int k0 = (s >> nlog) * 32, n0 = (s & ((1 << nlog) - 1)) * 32;
    int lr = threadIdx.x >> 5, lc = threadIdx.x & 31;
    #pragma unroll
    for (int i = 0; i < 4; i++) {
        int r = lr + i * 8;
        tile[r][lc] = src[(k0 + r) * N + n0 + lc];
    }
    __syncthreads();
    #pragma unroll
    for (int i = 0; i < 4; i++) {
        int r = lr + i * 8;
        dst[(n0 + r) * 1024 + k0 + lc] = f2bf(tile[lc][r]);
    }
}

// ------------------------------------------------ 128x64 bf16 MFMA GEMM, K=1024, BK=32
// ROPE=true: fused RoPE+RMSNorm epilogue (heads 0..15 q *0.125, 16..19 k, 20..23 v pass).
template <typename T, bool ROPE>
__global__ __launch_bounds__(256) void gemm_kernel(const unsigned short* __restrict__ A,
                                                   const unsigned short* __restrict__ Bt,
                                                   T* __restrict__ Cm, int Ni,
                                                   const float* __restrict__ cosb,
                                                   const float* __restrict__ sinb) {
    __shared__ __align__(16) unsigned short As[128 * 32];
    __shared__ __align__(16) unsigned short Bs[64 * 32];
    int m0 = blockIdx.x * 128;
    int head = blockIdx.y;
    int n0 = head * 64;
    int tid = threadIdx.x;
    int w = tid >> 6, lane = tid & 63;
    int col = lane & 15, quad = lane >> 4;
    int wm = w * 32;
    int ar = tid >> 2, ak = (tid & 3) * 8;

    f32x4 acc[2][4];
    #pragma unroll
    for (int mt = 0; mt < 2; mt++)
        #pragma unroll
        for (int nt = 0; nt < 4; nt++) acc[mt][nt] = (f32x4){0.f, 0.f, 0.f, 0.f};

    for (int k0 = 0; k0 < 1024; k0 += 32) {
        __builtin_amdgcn_global_load_lds(
            (const __attribute__((address_space(1))) unsigned int*)(A + (size_t)(m0 + ar) * 1024 + k0 + ak),
            (__attribute__((address_space(3))) unsigned int*)(As + ar * 32 + ak), 16, 0, 0);
        __builtin_amdgcn_global_load_lds(
            (const __attribute__((address_space(1))) unsigned int*)(A + (size_t)(m0 + ar + 64) * 1024 + k0 + ak),
            (__attribute__((address_space(3))) unsigned int*)(As + (ar + 64) * 32 + ak), 16, 0, 0);
        __builtin_amdgcn_global_load_lds(
            (const __attribute__((address_space(1))) unsigned int*)(Bt + (size_t)(n0 + ar) * 1024 + k0 + ak),
            (__attribute__((address_space(3))) unsigned int*)(Bs + ar * 32 + ak), 16, 0, 0);
        __syncthreads();
        bf16x8 af[2], bfr[4];
        #pragma unroll
        for (int mt = 0; mt < 2; mt++) af[mt]  = *(const bf16x8*)&As[(wm + mt * 16 + col) * 32 + quad * 8];
        #pragma unroll
        for (int nt = 0; nt < 4; nt++) bfr[nt] = *(const bf16x8*)&Bs[(nt * 16 + col) * 32 + quad * 8];
        #pragma unroll
        for (int mt = 0; mt < 2; mt++)
            #pragma unroll
            for (int nt = 0; nt < 4; nt++)
                acc[mt][nt] = __builtin_amdgcn_mfma_f32_16x16x32_bf16(af[mt], bfr[nt], acc[mt][nt], 0, 0, 0);
        __syncthreads();
    }

    if constexpr (ROPE) {
        if (head < H_ + KV_) {
            #pragma unroll
            for (int mt = 0; mt < 2; mt++)
                #pragma unroll
                for (int r = 0; r < 4; r++) {
                    int t = (m0 + wm + mt * 16 + quad * 4 + r) & (T_ - 1);
                    float nv[4];
                    #pragma unroll
                    for (int nt = 0; nt < 4; nt++) {
                        int i = (nt & 1) * 16 + col;
                        float c = cosb[t * 32 + i], s = sinb[t * 32 + i];
                        float v = acc[mt][nt][r], p = acc[mt][nt ^ 2][r];
                        nv[nt] = (nt < 2) ? (v * c + p * s) : (v * c - p * s);
                    }
                    float sq = nv[0] * nv[0] + nv[1] * nv[1] + nv[2] * nv[2] + nv[3] * nv[3];
                    sq += __shfl_xor(sq, 1, 64);
                    sq += __shfl_xor(sq, 2, 64);
                    sq += __shfl_xor(sq, 4, 64);
                    sq += __shfl_xor(sq, 8, 64);
                    float rr = rsqrtf(sq * (1.0f / 64.0f) + 1e-6f);
                    if (head < H_) rr *= 0.125f;
                    #pragma unroll
                    for (int nt = 0; nt < 4; nt++) acc[mt][nt][r] = nv[nt] * rr;
                }
        }
    }

    #pragma unroll
    for (int mt = 0; mt < 2; mt++)
        #pragma unroll
        for (int nt = 0; nt < 4; nt++)
            #pragma unroll
            for (int r = 0; r < 4; r++) {
                size_t idx = (size_t)(m0 + wm + mt * 16 + quad * 4 + r) * Ni + n0 + nt * 16 + col;
                if constexpr (sizeof(T) == 2) Cm[idx] = f2bf(acc[mt][nt][r]);
                else                          Cm[idx] = acc[mt][nt][r];
            }
}

// ------------------------------------------------ V -> V^T global: vtb[(b*KV+kvh)][d][t]
__global__ __launch_bounds__(256) void vtrans_kernel(const unsigned short* __restrict__ qkvb,
                                                     unsigned short* __restrict__ vtb) {
    __shared__ unsigned short tileb[64][72];
    int tile = blockIdx.x & 31;
    int bkv  = blockIdx.x >> 5;
    int b = bkv >> 2, kvh = bkv & 3;
    int tid = threadIdx.x;
    int t0 = tile * 64;
    #pragma unroll
    for (int i = 0; i < 2; i++) {
        int idx = tid + i * 256;
        int r = idx >> 3, d8 = (idx & 7) * 8;
        *(uint4*)&tileb[r][d8] =
            *(const uint4*)&qkvb[(size_t)(b * T_ + t0 + r) * NQKV_ + 1280 + kvh * 64 + d8];
    }
    __syncthreads();
    #pragma unroll
    for (int i = 0; i < 2; i++) {
        int idx = tid + i * 256;
        int dr = idx >> 3, t8 = (idx & 7) * 8;
        unsigned short tmp[8];
        #pragma unroll
        for (int j = 0; j < 8; j++) tmp[j] = tileb[t8 + j][dr];
        *(uint4*)&vtb[((size_t)(bkv * 64 + dr)) * T_ + t0 + t8] = *(uint4*)tmp;
    }
}

// ------------------------------------------------ MFMA flash attention: intra-block split-K
// block = (b, h, 32-row q-tile), 4 waves; wave w handles key-tiles kt = w, w+4, ...
// Fixed-max softmax (s in [-8,8]) makes partials ADDITIVE: O = sum O_w, l = sum l_w —
// no rescale, no per-iter barriers. K/V B-frags direct from global (L2-resident).
// End: 2 barriers + LDS-additive merge; Obuf aliases dead P space.
__global__ __launch_bounds__(256) void attn_kernel(const unsigned short* __restrict__ qkvb,
                                                   const unsigned short* __restrict__ vtb,
                                                   unsigned short* __restrict__ yb) {
    __shared__ __align__(16) char smem[4 * 32 * 64 * 4];   // 32 KB: Ps (loop) / Obuf fp32 (merge)
    __shared__ float lbuf[4][32];

    int bh = blockIdx.x & 31;
    int qt = 63 - (blockIdx.x >> 5);        // 0..63, big tiles dispatch first
    int b = bh >> 4, h = bh & 15, kvh = h >> 2;
    int tid = threadIdx.x;
    int w = tid >> 6, lane = tid & 63;
    int col = lane & 15, quad = lane >> 4;
    int t0 = qt * 32;
    int nkt = (t0 + 95) >> 6;               // 64-key tiles covering keys <= t0+31

    unsigned short* Ps = (unsigned short*)smem + w * (32 * PST_);
    float* Obuf = (float*)smem;

    const unsigned short* kptr = qkvb + (size_t)(b * T_) * NQKV_ + 1024 + kvh * 64;
    const unsigned short* vptr = vtb + (size_t)((b * KV_ + kvh) * 64) * T_;

    // Q A-frags (loop-invariant, registers; same for all 4 waves)
    bf16x8 aq[2][2];
    #pragma unroll
    for (int mt = 0; mt < 2; mt++)
        #pragma unroll
        for (int step = 0; step < 2; step++)
            aq[mt][step] = *(const bf16x8*)&qkvb[(size_t)(b * T_ + t0 + mt * 16 + col) * NQKV_
                                                 + h * 64 + quad * 8 + step * 32];
    bf16x8 ones;
    #pragma unroll
    for (int j = 0; j < 8; j++) ones[j] = (__bf16)1.0f;

    f32x4 o[2][4], lacc[2];
    #pragma unroll
    for (int mt = 0; mt < 2; mt++) {
        lacc[mt] = (f32x4){0.f, 0.f, 0.f, 0.f};
        #pragma unroll
        for (int nt = 0; nt < 4; nt++) o[mt][nt] = (f32x4){0.f, 0.f, 0.f, 0.f};
    }

    for (int kt = w; kt < nkt; kt += 4) {
        // S = Q K^T; K B-frags straight from global
        f32x4 sacc[2][4];
        #pragma unroll
        for (int mt = 0; mt < 2; mt++)
            #pragma unroll
            for (int nt = 0; nt < 4; nt++) sacc[mt][nt] = (f32x4){0.f, 0.f, 0.f, 0.f};
        #pragma unroll
        for (int step = 0; step < 2; step++) {
            bf16x8 kb[4];
            #pragma unroll
            for (int nt = 0; nt < 4; nt++)
                kb[nt] = *(const bf16x8*)&kptr[(size_t)(kt * 64 + nt * 16 + col) * NQKV_
                                               + quad * 8 + step * 32];
            #pragma unroll
            for (int nt = 0; nt < 4; nt++)
                #pragma unroll
                for (int mt = 0; mt < 2; mt++)
                    sacc[mt][nt] = __builtin_amdgcn_mfma_f32_16x16x32_bf16(aq[mt][step], kb[nt], sacc[mt][nt], 0, 0, 0);
        }
        // issue V loads; latency hides under exp/pack
        bf16x8 vb[2][4];
        #pragma unroll
        for (int step = 0; step < 2; step++)
            #pragma unroll
            for (int nt = 0; nt < 4; nt++)
                vb[step][nt] = *(const bf16x8*)&vptr[(size_t)(nt * 16 + col) * T_
                                                     + kt * 64 + quad * 8 + step * 32];
        if (kt == nkt - 1) {   // diagonal: causal mask
            #pragma unroll
            for (int mt = 0; mt < 2; mt++)
                #pragma unroll
                for (int nt = 0; nt < 4; nt++)
                    #pragma unroll
                    for (int r = 0; r < 4; r++)
                        if (kt * 64 + nt * 16 + col > t0 + mt * 16 + quad * 4 + r)
                            sacc[mt][nt][r] = -1e30f;
        }
        // p = exp(s - 8) -> wave-private P stripe (C-layout write, A-layout read)
        #pragma unroll
        for (int mt = 0; mt < 2; mt++)
            #pragma unroll
            for (int nt = 0; nt < 4; nt++)
                #pragma unroll
                for (int r = 0; r < 4; r++)
                    Ps[(mt * 16 + quad * 4 + r) * PST_ + nt * 16 + col] =
                        f2bf(__expf(sacc[mt][nt][r] - 8.0f));
        // O += P V ; l += P * ones
        #pragma unroll
        for (int step = 0; step < 2; step++) {
            bf16x8 ap[2];
            #pragma unroll
            for (int mt = 0; mt < 2; mt++)
                ap[mt] = *(const bf16x8*)&Ps[(mt * 16 + col) * PST_ + quad * 8 + step * 32];
            #pragma unroll
            for (int nt = 0; nt < 4; nt++)
                #pragma unroll
                for (int mt = 0; mt < 2; mt++)
                    o[mt][nt] = __builtin_amdgcn_mfma_f32_16x16x32_bf16(ap[mt], vb[step][nt], o[mt][nt], 0, 0, 0);
            #pragma unroll
            for (int mt = 0; mt < 2; mt++)
                lacc[mt] = __builtin_amdgcn_mfma_f32_16x16x32_bf16(ap[mt], ones, lacc[mt], 0, 0, 0);
        }
    }

    __syncthreads();   // all waves done with P space
    // write fp32 partials (Obuf aliases P space)
    #pragma unroll
    for (int mt = 0; mt < 2; mt++)
        #pragma unroll
        for (int nt = 0; nt < 4; nt++)
            #pragma unroll
            for (int r = 0; r < 4; r++)
                Obuf[w * 2048 + (mt * 16 + quad * 4 + r) * 64 + nt * 16 + col] = o[mt][nt][r];
    if (col == 0) {
        #pragma unroll
        for (int mt = 0; mt < 2; mt++)
            #pragma unroll
            for (int r = 0; r < 4; r++)
                lbuf[w][mt * 16 + quad * 4 + r] = lacc[mt][r];
    }
    __syncthreads();
    // additive merge + normalize + store (thread tid: row = tid>>3, dims (tid&7)*8..+7)
    {
        int row = tid >> 3, d0 = (tid & 7) * 8;
        float ls = lbuf[0][row] + lbuf[1][row] + lbuf[2][row] + lbuf[3][row];
        float inv = 1.0f / ls;
        float s[8];
        #pragma unroll
        for (int j = 0; j < 8; j++) s[j] = 0.f;
        #pragma unroll
        for (int wv = 0; wv < 4; wv++) {
            f32x4 p0 = *(const f32x4*)&Obuf[wv * 2048 + row * 64 + d0];
            f32x4 p1 = *(const f32x4*)&Obuf[wv * 2048 + row * 64 + d0 + 4];
            #pragma unroll
            for (int j = 0; j < 4; j++) { s[j] += p0[j]; s[4 + j] += p1[j]; }
        }
        unsigned short o8[8];
        #pragma unroll
        for (int j = 0; j < 8; j++) o8[j] = f2bf(s[j] * inv);
        *(uint4*)&yb[(size_t)(b * T_ + t0 + row) * C_ + h * 64 + d0] = *(uint4*)o8;
    }
}

// ---------------------------------------------------------------- launch
extern "C" void kernel_launch(void* const* d_in, const int* in_sizes, int n_in,
                              void* d_out, int out_size, void* d_ws, size_t ws_size,
                              hipStream_t stream) {
    const float* x    = (const float*)d_in[0];
    const float* cosb = (const float*)d_in[1];
    const float* sinb = (const float*)d_in[2];
    const float* Wq   = (const float*)d_in[3];
    const float* Wk   = (const float*)d_in[4];
    const float* Wv   = (const float*)d_in[5];
    const float* Wo   = (const float*)d_in[6];
    float* out = (float*)d_out;

    char* ws = (char*)d_ws;
    unsigned short* xb    = (unsigned short*)(ws);               // 8 MB (reused as yb)
    unsigned short* yb    = (unsigned short*)(ws);               // alias: xb dead after QKV GEMM
    unsigned short* wtqkv = (unsigned short*)(ws + ( 8u << 20)); // 3 MB
    unsigned short* wto   = (unsigned short*)(ws + (11u << 20)); // 2 MB
    unsigned short* qkvb  = (unsigned short*)(ws + (13u << 20)); // 12 MB
    unsigned short* vtb   = (unsigned short*)(ws + (25u << 20)); // 2 MB

    cast_x_kernel<<<4096, 256, 0, stream>>>(x, xb);
    transpose4_kernel<<<2560, 256, 0, stream>>>(Wq, Wk, Wv, Wo, wtqkv, wto);
    // QKV projection + fused RoPE/RMSNorm -> bf16 qkv
    gemm_kernel<unsigned short, true><<<dim3(32, 24), 256, 0, stream>>>(xb, wtqkv, qkvb, NQKV_, cosb, sinb);
    vtrans_kernel<<<256, 256, 0, stream>>>(qkvb, vtb);
    // split-K flash attention (4 waves per q-tile, additive merge) -> yb (bf16)
    attn_kernel<<<2048, 256, 0, stream>>>(qkvb, vtb, yb);
    // output projection -> fp32 out
    gemm_kernel<float, false><<<dim3(32, 16), 256, 0, stream>>>(yb, wto, out, C_, nullptr, nullptr);
}

// Round 9
// 194.350 us; speedup vs baseline: 1.3143x; 1.0083x over previous
//
#include <hip/hip_runtime.h>
#include <hip/hip_bf16.h>

#define B_   2
#define T_   2048
#define C_   1024
#define H_   16
#define KV_  4
#define HD_  64
#define M_   (B_*T_)     // 4096 tokens
#define NQKV_ 1536       // 1024 q + 256 k + 256 v
#define PST_ 72          // P LDS row stride (bf16): 144 B

typedef __bf16 bf16x8 __attribute__((ext_vector_type(8)));
typedef float  f32x4  __attribute__((ext_vector_type(4)));

static __device__ __forceinline__ unsigned short f2bf(float f) {
    __hip_bfloat16 h = __float2bfloat16(f);
    return __builtin_bit_cast(unsigned short, h);
}

// ---------------------------------------------------------------- prep: cast x + 4 weight transposes
__global__ void prep_kernel(const float* __restrict__ x, unsigned short* __restrict__ xb,
                            const float* __restrict__ Wq, const float* __restrict__ Wk,
                            const float* __restrict__ Wv, const float* __restrict__ Wo,
                            unsigned short* __restrict__ wtqkv, unsigned short* __restrict__ wto) {
    __shared__ float tile[32][33];
    int bid = blockIdx.x;
    if (bid < 4096) {   // cast x -> bf16
        int i = (bid * 256 + threadIdx.x) * 4;
        float4 v = *(const float4*)(x + i);
        ushort4 o = make_ushort4(f2bf(v.x), f2bf(v.y), f2bf(v.z), f2bf(v.w));
        *(ushort4*)(xb + i) = o;
        return;
    }
    bid -= 4096;
    const float* src; unsigned short* dst; int s, nlog;
    if (bid < 1024)      { src = Wq; dst = wtqkv;               s = bid;        nlog = 5; }
    else if (bid < 1280) { src = Wk; dst = wtqkv + 1024 * 1024; s = bid - 1024; nlog = 3; }
    else if (bid < 1536) { src = Wv; dst = wtqkv + 1280 * 1024; s = bid - 1280; nlog = 3; }
    else                 { src = Wo; dst = wto;                 s = bid - 1536; nlog = 5; }
    int N  = 32 << nlog;
    int k0 = (s >> nlog) * 32, n0 = (s & ((1 << nlog) - 1)) * 32;
    int lr = threadIdx.x >> 5, lc = threadIdx.x & 31;
    #pragma unroll
    for (int i = 0; i < 4; i++) {
        int r = lr + i * 8;
        tile[r][lc] = src[(k0 + r) * N + n0 + lc];
    }
    __syncthreads();
    #pragma unroll
    for (int i = 0; i < 4; i++) {
        int r = lr + i * 8;
        dst[(n0 + r) * 1024 + k0 + lc] = f2bf(tile[lc][r]);
    }
}

// ------------------------------------------------ 128x64 bf16 MFMA GEMM, K=1024, BK=64
// Two 32-col LDS panels per operand keep the bank-safe 64B row stride AND
// global_load_lds lane-contiguity. 16 MFMA per wave-iter, 16 barrier pairs total.
// ROPE=true: fused RoPE+RMSNorm epilogue (heads 0..15 q *0.125, 16..19 k, 20..23 v pass).
template <typename T, bool ROPE>
__global__ __launch_bounds__(256) void gemm_kernel(const unsigned short* __restrict__ A,
                                                   const unsigned short* __restrict__ Bt,
                                                   T* __restrict__ Cm, int Ni,
                                                   const float* __restrict__ cosb,
                                                   const float* __restrict__ sinb) {
    __shared__ __align__(16) unsigned short As[2][128 * 32];
    __shared__ __align__(16) unsigned short Bs[2][64 * 32];
    int m0 = blockIdx.x * 128;
    int head = blockIdx.y;
    int n0 = head * 64;
    int tid = threadIdx.x;
    int w = tid >> 6, lane = tid & 63;
    int col = lane & 15, quad = lane >> 4;
    int wm = w * 32;
    int ar = tid >> 2, ak = (tid & 3) * 8;   // 64 rows per pass, 32-elem panels

    f32x4 acc[2][4];
    #pragma unroll
    for (int mt = 0; mt < 2; mt++)
        #pragma unroll
        for (int nt = 0; nt < 4; nt++) acc[mt][nt] = (f32x4){0.f, 0.f, 0.f, 0.f};

    for (int k0 = 0; k0 < 1024; k0 += 64) {
        #pragma unroll
        for (int hh = 0; hh < 2; hh++) {
            __builtin_amdgcn_global_load_lds(
                (const __attribute__((address_space(1))) unsigned int*)(A + (size_t)(m0 + ar) * 1024 + k0 + hh * 32 + ak),
                (__attribute__((address_space(3))) unsigned int*)(&As[hh][ar * 32 + ak]), 16, 0, 0);
            __builtin_amdgcn_global_load_lds(
                (const __attribute__((address_space(1))) unsigned int*)(A + (size_t)(m0 + ar + 64) * 1024 + k0 + hh * 32 + ak),
                (__attribute__((address_space(3))) unsigned int*)(&As[hh][(ar + 64) * 32 + ak]), 16, 0, 0);
            __builtin_amdgcn_global_load_lds(
                (const __attribute__((address_space(1))) unsigned int*)(Bt + (size_t)(n0 + ar) * 1024 + k0 + hh * 32 + ak),
                (__attribute__((address_space(3))) unsigned int*)(&Bs[hh][ar * 32 + ak]), 16, 0, 0);
        }
        __syncthreads();
        bf16x8 af[2][2], bfr[4][2];
        #pragma unroll
        for (int hh = 0; hh < 2; hh++) {
            #pragma unroll
            for (int mt = 0; mt < 2; mt++) af[mt][hh]  = *(const bf16x8*)&As[hh][(wm + mt * 16 + col) * 32 + quad * 8];
            #pragma unroll
            for (int nt = 0; nt < 4; nt++) bfr[nt][hh] = *(const bf16x8*)&Bs[hh][(nt * 16 + col) * 32 + quad * 8];
        }
        #pragma unroll
        for (int hh = 0; hh < 2; hh++)
            #pragma unroll
            for (int mt = 0; mt < 2; mt++)
                #pragma unroll
                for (int nt = 0; nt < 4; nt++)
                    acc[mt][nt] = __builtin_amdgcn_mfma_f32_16x16x32_bf16(af[mt][hh], bfr[nt][hh], acc[mt][nt], 0, 0, 0);
        __syncthreads();
    }

    if constexpr (ROPE) {
        if (head < H_ + KV_) {
            #pragma unroll
            for (int mt = 0; mt < 2; mt++)
                #pragma unroll
                for (int r = 0; r < 4; r++) {
                    int t = (m0 + wm + mt * 16 + quad * 4 + r) & (T_ - 1);
                    float nv[4];
                    #pragma unroll
                    for (int nt = 0; nt < 4; nt++) {
                        int i = (nt & 1) * 16 + col;
                        float c = cosb[t * 32 + i], s = sinb[t * 32 + i];
                        float v = acc[mt][nt][r], p = acc[mt][nt ^ 2][r];
                        nv[nt] = (nt < 2) ? (v * c + p * s) : (v * c - p * s);
                    }
                    float sq = nv[0] * nv[0] + nv[1] * nv[1] + nv[2] * nv[2] + nv[3] * nv[3];
                    sq += __shfl_xor(sq, 1, 64);
                    sq += __shfl_xor(sq, 2, 64);
                    sq += __shfl_xor(sq, 4, 64);
                    sq += __shfl_xor(sq, 8, 64);
                    float rr = rsqrtf(sq * (1.0f / 64.0f) + 1e-6f);
                    if (head < H_) rr *= 0.125f;
                    #pragma unroll
                    for (int nt = 0; nt < 4; nt++) acc[mt][nt][r] = nv[nt] * rr;
                }
        }
    }

    #pragma unroll
    for (int mt = 0; mt < 2; mt++)
        #pragma unroll
        for (int nt = 0; nt < 4; nt++)
            #pragma unroll
            for (int r = 0; r < 4; r++) {
                size_t idx = (size_t)(m0 + wm + mt * 16 + quad * 4 + r) * Ni + n0 + nt * 16 + col;
                if constexpr (sizeof(T) == 2) Cm[idx] = f2bf(acc[mt][nt][r]);
                else                          Cm[idx] = acc[mt][nt][r];
            }
}

// ------------------------------------------------ V -> V^T global: vtb[(b*KV+kvh)][d][t]
__global__ __launch_bounds__(256) void vtrans_kernel(const unsigned short* __restrict__ qkvb,
                                                     unsigned short* __restrict__ vtb) {
    __shared__ unsigned short tileb[64][72];
    int tile = blockIdx.x & 31;
    int bkv  = blockIdx.x >> 5;
    int b = bkv >> 2, kvh = bkv & 3;
    int tid = threadIdx.x;
    int t0 = tile * 64;
    #pragma unroll
    for (int i = 0; i < 2; i++) {
        int idx = tid + i * 256;
        int r = idx >> 3, d8 = (idx & 7) * 8;
        *(uint4*)&tileb[r][d8] =
            *(const uint4*)&qkvb[(size_t)(b * T_ + t0 + r) * NQKV_ + 1280 + kvh * 64 + d8];
    }
    __syncthreads();
    #pragma unroll
    for (int i = 0; i < 2; i++) {
        int idx = tid + i * 256;
        int dr = idx >> 3, t8 = (idx & 7) * 8;
        unsigned short tmp[8];
        #pragma unroll
        for (int j = 0; j < 8; j++) tmp[j] = tileb[t8 + j][dr];
        *(uint4*)&vtb[((size_t)(bkv * 64 + dr)) * T_ + t0 + t8] = *(uint4*)tmp;
    }
}

// ------------------------------------------------ MFMA flash attention: split-K + SW pipeline
// block = (b, h, 32-row q-tile), 4 waves; wave w: key-tiles kt = w, w+4, ...
// Depth-2 pipeline per wave: iter i runs [K-load(i) | PV(i-1) | QK(i) | V-load(i) | exp(i)],
// so PV (MFMA) fills K-load latency and next iter's PV overlaps this iter's exp (VALU).
// Double P buffer per wave. Fixed-max softmax (s in [-8,8]) keeps partials additive.
__global__ __launch_bounds__(256) void attn_kernel(const unsigned short* __restrict__ qkvb,
                                                   const unsigned short* __restrict__ vtb,
                                                   unsigned short* __restrict__ yb) {
    __shared__ __align__(16) char smem[4 * 2 * 32 * PST_ * 2];   // 36.9 KB: Ps ping-pong / Obuf merge
    __shared__ float lbuf[4][32];

    int bh = blockIdx.x & 31;
    int qt = 63 - (blockIdx.x >> 5);        // big tiles dispatch first
    int b = bh >> 4, h = bh & 15, kvh = h >> 2;
    int tid = threadIdx.x;
    int w = tid >> 6, lane = tid & 63;
    int col = lane & 15, quad = lane >> 4;
    int t0 = qt * 32;
    int nkt = (t0 + 95) >> 6;               // 64-key tiles covering keys <= t0+31

    unsigned short* Pw = (unsigned short*)smem + w * (2 * 32 * PST_);
    float* Obuf = (float*)smem;

    const unsigned short* kptr = qkvb + (size_t)(b * T_) * NQKV_ + 1024 + kvh * 64;
    const unsigned short* vptr = vtb + (size_t)((b * KV_ + kvh) * 64) * T_;

    f32x4 o[2][4], lacc[2];
    #pragma unroll
    for (int mt = 0; mt < 2; mt++) {
        lacc[mt] = (f32x4){0.f, 0.f, 0.f, 0.f};
        #pragma unroll
        for (int nt = 0; nt < 4; nt++) o[mt][nt] = (f32x4){0.f, 0.f, 0.f, 0.f};
    }

    bf16x8 ones;
    #pragma unroll
    for (int j = 0; j < 8; j++) ones[j] = (__bf16)1.0f;

    if (w < nkt) {
        // Q A-frags (loop-invariant)
        bf16x8 aq[2][2];
        #pragma unroll
        for (int mt = 0; mt < 2; mt++)
            #pragma unroll
            for (int step = 0; step < 2; step++)
                aq[mt][step] = *(const bf16x8*)&qkvb[(size_t)(b * T_ + t0 + mt * 16 + col) * NQKV_
                                                     + h * 64 + quad * 8 + step * 32];
        bf16x8 vb[2][4];
        int cur = 0;

        // ---- prologue: tile w ----
        {
            int kt = w;
            bf16x8 kb0[4], kb1[4];
            #pragma unroll
            for (int nt = 0; nt < 4; nt++) {
                kb0[nt] = *(const bf16x8*)&kptr[(size_t)(kt * 64 + nt * 16 + col) * NQKV_ + quad * 8];
                kb1[nt] = *(const bf16x8*)&kptr[(size_t)(kt * 64 + nt * 16 + col) * NQKV_ + quad * 8 + 32];
            }
            f32x4 sacc[2][4];
            #pragma unroll
            for (int mt = 0; mt < 2; mt++)
                #pragma unroll
                for (int nt = 0; nt < 4; nt++) sacc[mt][nt] = (f32x4){0.f, 0.f, 0.f, 0.f};
            #pragma unroll
            for (int nt = 0; nt < 4; nt++)
                #pragma unroll
                for (int mt = 0; mt < 2; mt++) {
                    sacc[mt][nt] = __builtin_amdgcn_mfma_f32_16x16x32_bf16(aq[mt][0], kb0[nt], sacc[mt][nt], 0, 0, 0);
                    sacc[mt][nt] = __builtin_amdgcn_mfma_f32_16x16x32_bf16(aq[mt][1], kb1[nt], sacc[mt][nt], 0, 0, 0);
                }
            #pragma unroll
            for (int step = 0; step < 2; step++)
                #pragma unroll
                for (int nt = 0; nt < 4; nt++)
                    vb[step][nt] = *(const bf16x8*)&vptr[(size_t)(nt * 16 + col) * T_
                                                         + kt * 64 + quad * 8 + step * 32];
            if (kt == nkt - 1) {
                #pragma unroll
                for (int mt = 0; mt < 2; mt++)
                    #pragma unroll
                    for (int nt = 0; nt < 4; nt++)
                        #pragma unroll
                        for (int r = 0; r < 4; r++)
                            if (kt * 64 + nt * 16 + col > t0 + mt * 16 + quad * 4 + r)
                                sacc[mt][nt][r] = -1e30f;
            }
            #pragma unroll
            for (int mt = 0; mt < 2; mt++)
                #pragma unroll
                for (int nt = 0; nt < 4; nt++)
                    #pragma unroll
                    for (int r = 0; r < 4; r++)
                        Pw[cur * (32 * PST_) + (mt * 16 + quad * 4 + r) * PST_ + nt * 16 + col] =
                            f2bf(__expf(sacc[mt][nt][r] - 8.0f));
        }

        // ---- pipelined loop ----
        for (int kt = w + 4; kt < nkt; kt += 4) {
            // K loads for this tile (latency filled by PV below)
            bf16x8 kb0[4], kb1[4];
            #pragma unroll
            for (int nt = 0; nt < 4; nt++) {
                kb0[nt] = *(const bf16x8*)&kptr[(size_t)(kt * 64 + nt * 16 + col) * NQKV_ + quad * 8];
                kb1[nt] = *(const bf16x8*)&kptr[(size_t)(kt * 64 + nt * 16 + col) * NQKV_ + quad * 8 + 32];
            }
            // PV of previous tile (MFMA pipe; independent of the K loads)
            #pragma unroll
            for (int step = 0; step < 2; step++) {
                bf16x8 ap[2];
                #pragma unroll
                for (int mt = 0; mt < 2; mt++)
                    ap[mt] = *(const bf16x8*)&Pw[cur * (32 * PST_) + (mt * 16 + col) * PST_ + quad * 8 + step * 32];
                #pragma unroll
                for (int nt = 0; nt < 4; nt++)
                    #pragma unroll
                    for (int mt = 0; mt < 2; mt++)
                        o[mt][nt] = __builtin_amdgcn_mfma_f32_16x16x32_bf16(ap[mt], vb[step][nt], o[mt][nt], 0, 0, 0);
                #pragma unroll
                for (int mt = 0; mt < 2; mt++)
                    lacc[mt] = __builtin_amdgcn_mfma_f32_16x16x32_bf16(ap[mt], ones, lacc[mt], 0, 0, 0);
            }
            // QK of this tile
            f32x4 sacc[2][4];
            #pragma unroll
            for (int mt = 0; mt < 2; mt++)
                #pragma unroll
                for (int nt = 0; nt < 4; nt++) sacc[mt][nt] = (f32x4){0.f, 0.f, 0.f, 0.f};
            #pragma unroll
            for (int nt = 0; nt < 4; nt++)
                #pragma unroll
                for (int mt = 0; mt < 2; mt++) {
                    sacc[mt][nt] = __builtin_amdgcn_mfma_f32_16x16x32_bf16(aq[mt][0], kb0[nt], sacc[mt][nt], 0, 0, 0);
                    sacc[mt][nt] = __builtin_amdgcn_mfma_f32_16x16x32_bf16(aq[mt][1], kb1[nt], sacc[mt][nt], 0, 0, 0);
                }
            // V loads for this tile (consumed by next iter's PV; prev vb just consumed)
            #pragma unroll
            for (int step = 0; step < 2; step++)
                #pragma unroll
                for (int nt = 0; nt < 4; nt++)
                    vb[step][nt] = *(const bf16x8*)&vptr[(size_t)(nt * 16 + col) * T_
                                                         + kt * 64 + quad * 8 + step * 32];
            if (kt == nkt - 1) {
                #pragma unroll
                for (int mt = 0; mt < 2; mt++)
                    #pragma unroll
                    for (int nt = 0; nt < 4; nt++)
                        #pragma unroll
                        for (int r = 0; r < 4; r++)
                            if (kt * 64 + nt * 16 + col > t0 + mt * 16 + quad * 4 + r)
                                sacc[mt][nt][r] = -1e30f;
            }
            // exp into the other P buffer (VALU; overlaps next iter's PV MFMAs)
            cur ^= 1;
            #pragma unroll
            for (int mt = 0; mt < 2; mt++)
                #pragma unroll
                for (int nt = 0; nt < 4; nt++)
                    #pragma unroll
                    for (int r = 0; r < 4; r++)
                        Pw[cur * (32 * PST_) + (mt * 16 + quad * 4 + r) * PST_ + nt * 16 + col] =
                            f2bf(__expf(sacc[mt][nt][r] - 8.0f));
        }

        // ---- drain: PV of the last tile ----
        #pragma unroll
        for (int step = 0; step < 2; step++) {
            bf16x8 ap[2];
            #pragma unroll
            for (int mt = 0; mt < 2; mt++)
                ap[mt] = *(const bf16x8*)&Pw[cur * (32 * PST_) + (mt * 16 + col) * PST_ + quad * 8 + step * 32];
            #pragma unroll
            for (int nt = 0; nt < 4; nt++)
                #pragma unroll
                for (int mt = 0; mt < 2; mt++)
                    o[mt][nt] = __builtin_amdgcn_mfma_f32_16x16x32_bf16(ap[mt], vb[step][nt], o[mt][nt], 0, 0, 0);
            #pragma unroll
            for (int mt = 0; mt < 2; mt++)
                lacc[mt] = __builtin_amdgcn_mfma_f32_16x16x32_bf16(ap[mt], ones, lacc[mt], 0, 0, 0);
        }
    }

    __syncthreads();   // all waves done with P space
    #pragma unroll
    for (int mt = 0; mt < 2; mt++)
        #pragma unroll
        for (int nt = 0; nt < 4; nt++)
            #pragma unroll
            for (int r = 0; r < 4; r++)
                Obuf[w * 2048 + (mt * 16 + quad * 4 + r) * 64 + nt * 16 + col] = o[mt][nt][r];
    if (col == 0) {
        #pragma unroll
        for (int mt = 0; mt < 2; mt++)
            #pragma unroll
            for (int r = 0; r < 4; r++)
                lbuf[w][mt * 16 + quad * 4 + r] = lacc[mt][r];
    }
    __syncthreads();
    {
        int row = tid >> 3, d0 = (tid & 7) * 8;
        float ls = lbuf[0][row] + lbuf[1][row] + lbuf[2][row] + lbuf[3][row];
        float inv = 1.0f / ls;
        float s[8];
        #pragma unroll
        for (int j = 0; j < 8; j++) s[j] = 0.f;
        #pragma unroll
        for (int wv = 0; wv < 4; wv++) {
            f32x4 p0 = *(const f32x4*)&Obuf[wv * 2048 + row * 64 + d0];
            f32x4 p1 = *(const f32x4*)&Obuf[wv * 2048 + row * 64 + d0 + 4];
            #pragma unroll
            for (int j = 0; j < 4; j++) { s[j] += p0[j]; s[4 + j] += p1[j]; }
        }
        unsigned short o8[8];
        #pragma unroll
        for (int j = 0; j < 8; j++) o8[j] = f2bf(s[j] * inv);
        *(uint4*)&yb[(size_t)(b * T_ + t0 + row) * C_ + h * 64 + d0] = *(uint4*)o8;
    }
}

// ---------------------------------------------------------------- launch
extern "C" void kernel_launch(void* const* d_in, const int* in_sizes, int n_in,
                              void* d_out, int out_size, void* d_ws, size_t ws_size,
                              hipStream_t stream) {
    const float* x    = (const float*)d_in[0];
    const float* cosb = (const float*)d_in[1];
    const float* sinb = (const float*)d_in[2];
    const float* Wq   = (const float*)d_in[3];
    const float* Wk   = (const float*)d_in[4];
    const float* Wv   = (const float*)d_in[5];
    const float* Wo   = (const float*)d_in[6];
    float* out = (float*)d_out;

    char* ws = (char*)d_ws;
    unsigned short* xb    = (unsigned short*)(ws);               // 8 MB (reused as yb)
    unsigned short* yb    = (unsigned short*)(ws);               // alias: xb dead after QKV GEMM
    unsigned short* wtqkv = (unsigned short*)(ws + ( 8u << 20)); // 3 MB
    unsigned short* wto   = (unsigned short*)(ws + (11u << 20)); // 2 MB
    unsigned short* qkvb  = (unsigned short*)(ws + (13u << 20)); // 12 MB
    unsigned short* vtb   = (unsigned short*)(ws + (25u << 20)); // 2 MB

    prep_kernel<<<4096 + 2560, 256, 0, stream>>>(x, xb, Wq, Wk, Wv, Wo, wtqkv, wto);
    // QKV projection + fused RoPE/RMSNorm -> bf16 qkv
    gemm_kernel<unsigned short, true><<<dim3(32, 24), 256, 0, stream>>>(xb, wtqkv, qkvb, NQKV_, cosb, sinb);
    vtrans_kernel<<<256, 256, 0, stream>>>(qkvb, vtb);
    // split-K + software-pipelined flash attention -> yb (bf16)
    attn_kernel<<<2048, 256, 0, stream>>>(qkvb, vtb, yb);
    // output projection -> fp32 out
    gemm_kernel<float, false><<<dim3(32, 16), 256, 0, stream>>>(yb, wto, out, C_, nullptr, nullptr);
}

// Round 10
// 191.449 us; speedup vs baseline: 1.3342x; 1.0152x over previous
//
#include <hip/hip_runtime.h>
#include <hip/hip_bf16.h>

#define B_   2
#define T_   2048
#define C_   1024
#define H_   16
#define KV_  4
#define HD_  64
#define M_   (B_*T_)     // 4096 tokens
#define NQKV_ 1536       // 1024 q + 256 k + 256 v (v region unused now)
#define PST_ 72          // P LDS row stride (bf16): 144 B
#define M8L2E_ 11.5415603f   // 8 * log2(e)

typedef __bf16 bf16x8 __attribute__((ext_vector_type(8)));
typedef float  f32x4  __attribute__((ext_vector_type(4)));

static __device__ __forceinline__ unsigned short f2bf(float f) {
    __hip_bfloat16 h = __float2bfloat16(f);
    return __builtin_bit_cast(unsigned short, h);
}
static __device__ __forceinline__ unsigned int pk2(float a, float b) {
    return (unsigned int)f2bf(a) | ((unsigned int)f2bf(b) << 16);
}

// ---------------------------------------------------------------- prep: cast x + 4 weight transposes
__global__ void prep_kernel(const float* __restrict__ x, unsigned short* __restrict__ xb,
                            const float* __restrict__ Wq, const float* __restrict__ Wk,
                            const float* __restrict__ Wv, const float* __restrict__ Wo,
                            unsigned short* __restrict__ wtqkv, unsigned short* __restrict__ wto) {
    __shared__ float tile[32][33];
    int bid = blockIdx.x;
    if (bid < 4096) {   // cast x -> bf16
        int i = (bid * 256 + threadIdx.x) * 4;
        float4 v = *(const float4*)(x + i);
        ushort4 o = make_ushort4(f2bf(v.x), f2bf(v.y), f2bf(v.z), f2bf(v.w));
        *(ushort4*)(xb + i) = o;
        return;
    }
    bid -= 4096;
    const float* src; unsigned short* dst; int s, nlog;
    if (bid < 1024)      { src = Wq; dst = wtqkv;               s = bid;        nlog = 5; }
    else if (bid < 1280) { src = Wk; dst = wtqkv + 1024 * 1024; s = bid - 1024; nlog = 3; }
    else if (bid < 1536) { src = Wv; dst = wtqkv + 1280 * 1024; s = bid - 1280; nlog = 3; }
    else                 { src = Wo; dst = wto;                 s = bid - 1536; nlog = 5; }
    int N  = 32 << nlog;
    int k0 = (s >> nlog) * 32, n0 = (s & ((1 << nlog) - 1)) * 32;
    int lr = threadIdx.x >> 5, lc = threadIdx.x & 31;
    #pragma unroll
    for (int i = 0; i < 4; i++) {
        int r = lr + i * 8;
        tile[r][lc] = src[(k0 + r) * N + n0 + lc];
    }
    __syncthreads();
    #pragma unroll
    for (int i = 0; i < 4; i++) {
        int r = lr + i * 8;
        dst[(n0 + r) * 1024 + k0 + lc] = f2bf(tile[lc][r]);
    }
}

// ------------------------------------------------ 128x64 bf16 MFMA GEMM, K=1024, BK=64
// grid = (heads, m-blocks): head-major so same-A-panel blocks are temporally adjacent (L2-hot).
// ROPE=true: heads 0..15 q (RoPE+RMS, *0.125*log2e), 16..19 k (RoPE+RMS),
//            20..23 v -> written TRANSPOSED straight to vtb[(b*KV+kvh)*64+d][t].
template <typename T, bool ROPE>
__global__ __launch_bounds__(256) void gemm_kernel(const unsigned short* __restrict__ A,
                                                   const unsigned short* __restrict__ Bt,
                                                   T* __restrict__ Cm, int Ni,
                                                   const float* __restrict__ cosb,
                                                   const float* __restrict__ sinb,
                                                   unsigned short* __restrict__ vtb) {
    __shared__ __align__(16) unsigned short As[2][128 * 32];
    __shared__ __align__(16) unsigned short Bs[2][64 * 32];
    int head = blockIdx.x;
    int m0 = blockIdx.y * 128;
    int n0 = head * 64;
    int tid = threadIdx.x;
    int w = tid >> 6, lane = tid & 63;
    int col = lane & 15, quad = lane >> 4;
    int wm = w * 32;
    int ar = tid >> 2, ak = (tid & 3) * 8;

    f32x4 acc[2][4];
    #pragma unroll
    for (int mt = 0; mt < 2; mt++)
        #pragma unroll
        for (int nt = 0; nt < 4; nt++) acc[mt][nt] = (f32x4){0.f, 0.f, 0.f, 0.f};

    for (int k0 = 0; k0 < 1024; k0 += 64) {
        #pragma unroll
        for (int hh = 0; hh < 2; hh++) {
            __builtin_amdgcn_global_load_lds(
                (const __attribute__((address_space(1))) unsigned int*)(A + (size_t)(m0 + ar) * 1024 + k0 + hh * 32 + ak),
                (__attribute__((address_space(3))) unsigned int*)(&As[hh][ar * 32 + ak]), 16, 0, 0);
            __builtin_amdgcn_global_load_lds(
                (const __attribute__((address_space(1))) unsigned int*)(A + (size_t)(m0 + ar + 64) * 1024 + k0 + hh * 32 + ak),
                (__attribute__((address_space(3))) unsigned int*)(&As[hh][(ar + 64) * 32 + ak]), 16, 0, 0);
            __builtin_amdgcn_global_load_lds(
                (const __attribute__((address_space(1))) unsigned int*)(Bt + (size_t)(n0 + ar) * 1024 + k0 + hh * 32 + ak),
                (__attribute__((address_space(3))) unsigned int*)(&Bs[hh][ar * 32 + ak]), 16, 0, 0);
        }
        __syncthreads();
        bf16x8 af[2][2], bfr[4][2];
        #pragma unroll
        for (int hh = 0; hh < 2; hh++) {
            #pragma unroll
            for (int mt = 0; mt < 2; mt++) af[mt][hh]  = *(const bf16x8*)&As[hh][(wm + mt * 16 + col) * 32 + quad * 8];
            #pragma unroll
            for (int nt = 0; nt < 4; nt++) bfr[nt][hh] = *(const bf16x8*)&Bs[hh][(nt * 16 + col) * 32 + quad * 8];
        }
        #pragma unroll
        for (int hh = 0; hh < 2; hh++)
            #pragma unroll
            for (int mt = 0; mt < 2; mt++)
                #pragma unroll
                for (int nt = 0; nt < 4; nt++)
                    acc[mt][nt] = __builtin_amdgcn_mfma_f32_16x16x32_bf16(af[mt][hh], bfr[nt][hh], acc[mt][nt], 0, 0, 0);
        __syncthreads();
    }

    if constexpr (ROPE) {
        if (head >= H_ + KV_) {
            // v head: write transposed to vtb[(b*KV+kvh)*64 + d][t], packed 4x bf16 (t-contig)
            int kvh = head - (H_ + KV_);
            int b = m0 >> 11;
            #pragma unroll
            for (int mt = 0; mt < 2; mt++) {
                int tb = (m0 + wm + mt * 16 + quad * 4) & (T_ - 1);
                #pragma unroll
                for (int nt = 0; nt < 4; nt++) {
                    int d = nt * 16 + col;
                    uint2 pv;
                    pv.x = pk2(acc[mt][nt][0], acc[mt][nt][1]);
                    pv.y = pk2(acc[mt][nt][2], acc[mt][nt][3]);
                    *(uint2*)&vtb[((size_t)((b * KV_ + kvh) * 64 + d)) * T_ + tb] = pv;
                }
            }
            return;
        }
        // q/k head: RoPE + RMSNorm
        #pragma unroll
        for (int mt = 0; mt < 2; mt++)
            #pragma unroll
            for (int r = 0; r < 4; r++) {
                int t = (m0 + wm + mt * 16 + quad * 4 + r) & (T_ - 1);
                float nv[4];
                #pragma unroll
                for (int nt = 0; nt < 4; nt++) {
                    int i = (nt & 1) * 16 + col;
                    float c = cosb[t * 32 + i], s = sinb[t * 32 + i];
                    float v = acc[mt][nt][r], p = acc[mt][nt ^ 2][r];
                    nv[nt] = (nt < 2) ? (v * c + p * s) : (v * c - p * s);
                }
                float sq = nv[0] * nv[0] + nv[1] * nv[1] + nv[2] * nv[2] + nv[3] * nv[3];
                sq += __shfl_xor(sq, 1, 64);
                sq += __shfl_xor(sq, 2, 64);
                sq += __shfl_xor(sq, 4, 64);
                sq += __shfl_xor(sq, 8, 64);
                float rr = rsqrtf(sq * (1.0f / 64.0f) + 1e-6f);
                if (head < H_) rr *= 0.125f * 1.44269504f;   // attn scale * log2(e) folded into q
                #pragma unroll
                for (int nt = 0; nt < 4; nt++) acc[mt][nt][r] = nv[nt] * rr;
            }
    }

    #pragma unroll
    for (int mt = 0; mt < 2; mt++)
        #pragma unroll
        for (int nt = 0; nt < 4; nt++)
            #pragma unroll
            for (int r = 0; r < 4; r++) {
                size_t idx = (size_t)(m0 + wm + mt * 16 + quad * 4 + r) * Ni + n0 + nt * 16 + col;
                if constexpr (sizeof(T) == 2) Cm[idx] = f2bf(acc[mt][nt][r]);
                else                          Cm[idx] = acc[mt][nt][r];
            }
}

// ------------------------------------------------ MFMA flash attention: split-K, S^T trick
// block = (b, h, 32-row q-tile), 4 waves; wave w: key-tiles kt = w, w+4, ...
// QK^T computed TRANSPOSED (A=K, B=Q) so each lane's 4 acc values have consecutive keys
// -> P written to LDS as 8 ds_write_b64 (was 32 ds_write_b16). PV reads P q-major (b128).
// Fixed-max softmax via exp2 (log2e folded into q): p = 2^(s' - 8*log2e), additive partials.
__global__ __launch_bounds__(256) void attn_kernel(const unsigned short* __restrict__ qkvb,
                                                   const unsigned short* __restrict__ vtb,
                                                   unsigned short* __restrict__ yb) {
    __shared__ __align__(16) char smem[4 * 32 * 64 * 4];   // 32 KB: P stripes (loop) / Obuf fp32 (merge)
    __shared__ float lbuf[4][32];

    int bh = blockIdx.x & 31;
    int qt = 63 - (blockIdx.x >> 5);        // big tiles dispatch first
    int b = bh >> 4, h = bh & 15, kvh = h >> 2;
    int tid = threadIdx.x;
    int w = tid >> 6, lane = tid & 63;
    int col = lane & 15, quad = lane >> 4;
    int t0 = qt * 32;
    int nkt = (t0 + 95) >> 6;               // 64-key tiles covering keys <= t0+31

    unsigned short* Ps = (unsigned short*)smem + w * (32 * PST_);
    float* Obuf = (float*)smem;

    const unsigned short* kptr = qkvb + (size_t)(b * T_) * NQKV_ + 1024 + kvh * 64;
    const unsigned short* vptr = vtb + (size_t)((b * KV_ + kvh) * 64) * T_;

    // Q B-frags (loop-invariant): lane(col=q, quad) holds Q[t0+ntq*16+col][quad*8+step*32..]
    bf16x8 aq[2][2];
    #pragma unroll
    for (int ntq = 0; ntq < 2; ntq++)
        #pragma unroll
        for (int step = 0; step < 2; step++)
            aq[ntq][step] = *(const bf16x8*)&qkvb[(size_t)(b * T_ + t0 + ntq * 16 + col) * NQKV_
                                                  + h * 64 + quad * 8 + step * 32];
    bf16x8 ones;
    #pragma unroll
    for (int j = 0; j < 8; j++) ones[j] = (__bf16)1.0f;

    f32x4 o[2][4], lacc[2];
    #pragma unroll
    for (int mt = 0; mt < 2; mt++) {
        lacc[mt] = (f32x4){0.f, 0.f, 0.f, 0.f};
        #pragma unroll
        for (int nt = 0; nt < 4; nt++) o[mt][nt] = (f32x4){0.f, 0.f, 0.f, 0.f};
    }

    for (int kt = w; kt < nkt; kt += 4) {
        // S^T = K Q^T : A-frag = K rows (key), B-frag = Q
        f32x4 sacc[4][2];
        #pragma unroll
        for (int mtk = 0; mtk < 4; mtk++)
            #pragma unroll
            for (int ntq = 0; ntq < 2; ntq++) sacc[mtk][ntq] = (f32x4){0.f, 0.f, 0.f, 0.f};
        #pragma unroll
        for (int step = 0; step < 2; step++) {
            bf16x8 kb[4];
            #pragma unroll
            for (int mtk = 0; mtk < 4; mtk++)
                kb[mtk] = *(const bf16x8*)&kptr[(size_t)(kt * 64 + mtk * 16 + col) * NQKV_
                                                + quad * 8 + step * 32];
            #pragma unroll
            for (int mtk = 0; mtk < 4; mtk++)
                #pragma unroll
                for (int ntq = 0; ntq < 2; ntq++)
                    sacc[mtk][ntq] = __builtin_amdgcn_mfma_f32_16x16x32_bf16(kb[mtk], aq[ntq][step], sacc[mtk][ntq], 0, 0, 0);
        }
        // issue V loads; latency hides under exp/pack
        bf16x8 vb[2][4];
        #pragma unroll
        for (int step = 0; step < 2; step++)
            #pragma unroll
            for (int ntd = 0; ntd < 4; ntd++)
                vb[step][ntd] = *(const bf16x8*)&vptr[(size_t)(ntd * 16 + col) * T_
                                                      + kt * 64 + quad * 8 + step * 32];
        if (kt == nkt - 1) {   // diagonal: causal mask (S^T indices: row=key, col=q)
            #pragma unroll
            for (int mtk = 0; mtk < 4; mtk++)
                #pragma unroll
                for (int ntq = 0; ntq < 2; ntq++)
                    #pragma unroll
                    for (int r = 0; r < 4; r++)
                        if (kt * 64 + mtk * 16 + quad * 4 + r > t0 + ntq * 16 + col)
                            sacc[mtk][ntq][r] = -1e30f;
        }
        // p = 2^(s' - 8*log2e); lane's 4 values are key-consecutive -> one b64 write each
        #pragma unroll
        for (int mtk = 0; mtk < 4; mtk++)
            #pragma unroll
            for (int ntq = 0; ntq < 2; ntq++) {
                uint2 pw;
                pw.x = pk2(exp2f(sacc[mtk][ntq][0] - M8L2E_), exp2f(sacc[mtk][ntq][1] - M8L2E_));
                pw.y = pk2(exp2f(sacc[mtk][ntq][2] - M8L2E_), exp2f(sacc[mtk][ntq][3] - M8L2E_));
                *(uint2*)&Ps[(ntq * 16 + col) * PST_ + mtk * 16 + quad * 4] = pw;
            }
        // O += P V ; l += P * ones  (P read q-major as A-frag, b128)
        #pragma unroll
        for (int step = 0; step < 2; step++) {
            bf16x8 ap[2];
            #pragma unroll
            for (int mtq = 0; mtq < 2; mtq++)
                ap[mtq] = *(const bf16x8*)&Ps[(mtq * 16 + col) * PST_ + quad * 8 + step * 32];
            #pragma unroll
            for (int ntd = 0; ntd < 4; ntd++)
                #pragma unroll
                for (int mtq = 0; mtq < 2; mtq++)
                    o[mtq][ntd] = __builtin_amdgcn_mfma_f32_16x16x32_bf16(ap[mtq], vb[step][ntd], o[mtq][ntd], 0, 0, 0);
            #pragma unroll
            for (int mtq = 0; mtq < 2; mtq++)
                lacc[mtq] = __builtin_amdgcn_mfma_f32_16x16x32_bf16(ap[mtq], ones, lacc[mtq], 0, 0, 0);
        }
    }

    __syncthreads();   // all waves done with P space
    #pragma unroll
    for (int mt = 0; mt < 2; mt++)
        #pragma unroll
        for (int nt = 0; nt < 4; nt++)
            #pragma unroll
            for (int r = 0; r < 4; r++)
                Obuf[w * 2048 + (mt * 16 + quad * 4 + r) * 64 + nt * 16 + col] = o[mt][nt][r];
    if (col == 0) {
        #pragma unroll
        for (int mt = 0; mt < 2; mt++)
            #pragma unroll
            for (int r = 0; r < 4; r++)
                lbuf[w][mt * 16 + quad * 4 + r] = lacc[mt][r];
    }
    __syncthreads();
    {
        int row = tid >> 3, d0 = (tid & 7) * 8;
        float ls = lbuf[0][row] + lbuf[1][row] + lbuf[2][row] + lbuf[3][row];
        float inv = 1.0f / ls;
        float s[8];
        #pragma unroll
        for (int j = 0; j < 8; j++) s[j] = 0.f;
        #pragma unroll
        for (int wv = 0; wv < 4; wv++) {
            f32x4 p0 = *(const f32x4*)&Obuf[wv * 2048 + row * 64 + d0];
            f32x4 p1 = *(const f32x4*)&Obuf[wv * 2048 + row * 64 + d0 + 4];
            #pragma unroll
            for (int j = 0; j < 4; j++) { s[j] += p0[j]; s[4 + j] += p1[j]; }
        }
        unsigned short o8[8];
        #pragma unroll
        for (int j = 0; j < 8; j++) o8[j] = f2bf(s[j] * inv);
        *(uint4*)&yb[(size_t)(b * T_ + t0 + row) * C_ + h * 64 + d0] = *(uint4*)o8;
    }
}

// ---------------------------------------------------------------- launch
extern "C" void kernel_launch(void* const* d_in, const int* in_sizes, int n_in,
                              void* d_out, int out_size, void* d_ws, size_t ws_size,
                              hipStream_t stream) {
    const float* x    = (const float*)d_in[0];
    const float* cosb = (const float*)d_in[1];
    const float* sinb = (const float*)d_in[2];
    const float* Wq   = (const float*)d_in[3];
    const float* Wk   = (const float*)d_in[4];
    const float* Wv   = (const float*)d_in[5];
    const float* Wo   = (const float*)d_in[6];
    float* out = (float*)d_out;

    char* ws = (char*)d_ws;
    unsigned short* xb    = (unsigned short*)(ws);               // 8 MB (reused as yb)
    unsigned short* yb    = (unsigned short*)(ws);               // alias: xb dead after QKV GEMM
    unsigned short* wtqkv = (unsigned short*)(ws + ( 8u << 20)); // 3 MB
    unsigned short* wto   = (unsigned short*)(ws + (11u << 20)); // 2 MB
    unsigned short* qkvb  = (unsigned short*)(ws + (13u << 20)); // 12 MB (v region unused)
    unsigned short* vtb   = (unsigned short*)(ws + (25u << 20)); // 2 MB

    prep_kernel<<<4096 + 2560, 256, 0, stream>>>(x, xb, Wq, Wk, Wv, Wo, wtqkv, wto);
    // QKV projection + fused RoPE/RMSNorm (q,k) + fused V-transpose (v -> vtb)
    gemm_kernel<unsigned short, true><<<dim3(24, 32), 256, 0, stream>>>(xb, wtqkv, qkvb, NQKV_, cosb, sinb, vtb);
    // split-K flash attention (S^T + b64 P-writes + exp2) -> yb (bf16)
    attn_kernel<<<2048, 256, 0, stream>>>(qkvb, vtb, yb);
    // output projection -> fp32 out
    gemm_kernel<float, false><<<dim3(16, 32), 256, 0, stream>>>(yb, wto, out, C_, nullptr, nullptr, nullptr);
}